// Round 12
// baseline (247.901 us; speedup 1.0000x reference)
//
#include <hip/hip_runtime.h>
#include <math.h>

// Shapes (fixed): B=4, C=256, H=W=64, N=4096, 4C=1024, c8=32, r=16.

typedef float f32x4 __attribute__((ext_vector_type(4)));
typedef short s16x8 __attribute__((ext_vector_type(8)));
union FRAG { uint4 u; s16x8 s; };

__device__ __forceinline__ unsigned short f2bf(float f) {
    union { float f; unsigned int u; } v; v.f = f;
    unsigned int r = v.u + 0x7FFFu + ((v.u >> 16) & 1u);
    return (unsigned short)(r >> 16);
}

// ---------------------------------------------------------------------------
// K1: per-(b,c) plane -> block-mean pyramid + feats.
// Carries 80 extra blocks (bc >= 1024) doing the WB bf16 weight-cast.
// ---------------------------------------------------------------------------
__global__ __launch_bounds__(256) void k_pyramid(
    const float* __restrict__ xin,
    float* __restrict__ bm2, float* __restrict__ bm4, float* __restrict__ bm8,
    float* __restrict__ featA, float* __restrict__ fm1, float* __restrict__ fm2,
    float* __restrict__ fm4, float* __restrict__ fm8,
    const float* __restrict__ Wq, const float* __restrict__ Wk,
    const float* __restrict__ Wv, unsigned short* __restrict__ WB)
{
    __shared__ float sx[4096];
    __shared__ float s2[1024];
    __shared__ float s4[256];
    __shared__ float wred[4][8];
    const int bc = blockIdx.x;
    const int t = threadIdx.x;
    if (bc >= 1024) {
        const int e0 = (bc - 1024) * 1024 + t * 4;
        const int o = e0 >> 8, col = e0 & 255;
        const float* row = (o < 32) ? (Wq + (size_t)o * 1024)
                          : (o < 64) ? (Wk + (size_t)(o - 32) * 1024)
                                     : (Wv + (size_t)(o - 64) * 1024);
        float4 v = *(const float4*)(row + 768 + col);
        uint2 pk;
        pk.x = (unsigned)f2bf(v.x) | ((unsigned)f2bf(v.y) << 16);
        pk.y = (unsigned)f2bf(v.z) | ((unsigned)f2bf(v.w) << 16);
        *(uint2*)(WB + e0) = pk;
        return;
    }
    const float* xp = xin + (size_t)bc * 4096;
    float sum = 0.f, mx = -1e30f;
    for (int r = 0; r < 4; r++) {
        int i4 = t + 256 * r;
        float4 v = ((const float4*)xp)[i4];
        sum += v.x + v.y + v.z + v.w;
        mx = fmaxf(mx, fmaxf(fmaxf(v.x, v.y), fmaxf(v.z, v.w)));
        ((float4*)sx)[i4] = v;
    }
    __syncthreads();
    float mx2 = -1e30f;
    for (int r = 0; r < 4; r++) {
        int i = t + 256 * r;
        int r2 = i >> 5, c2 = i & 31;
        int p0 = 128 * r2 + 2 * c2;
        float v = 0.25f * (sx[p0] + sx[p0 + 1] + sx[p0 + 64] + sx[p0 + 65]);
        s2[i] = v;
        bm2[(size_t)bc * 1024 + i] = v;
        mx2 = fmaxf(mx2, v);
    }
    __syncthreads();
    float mx4;
    {
        int r4 = t >> 4, c4 = t & 15;
        int p0 = 64 * r4 + 2 * c4;
        float v = 0.25f * (s2[p0] + s2[p0 + 1] + s2[p0 + 32] + s2[p0 + 33]);
        s4[t] = v;
        bm4[(size_t)bc * 256 + t] = v;
        mx4 = v;
    }
    __syncthreads();
    float mx8 = -1e30f;
    if (t < 64) {
        int r8 = t >> 3, c8 = t & 7;
        int p0 = 32 * r8 + 2 * c8;
        float v = 0.25f * (s4[p0] + s4[p0 + 1] + s4[p0 + 16] + s4[p0 + 17]);
        bm8[(size_t)bc * 64 + t] = v;
        mx8 = v;
    }
    {
        float vs = sum, v1 = mx, v2 = mx2, v4 = mx4, v8 = mx8;
        #pragma unroll
        for (int o = 1; o < 64; o <<= 1) {
            vs += __shfl_xor(vs, o);
            v1 = fmaxf(v1, __shfl_xor(v1, o));
            v2 = fmaxf(v2, __shfl_xor(v2, o));
            v4 = fmaxf(v4, __shfl_xor(v4, o));
            v8 = fmaxf(v8, __shfl_xor(v8, o));
        }
        if ((t & 63) == 0) {
            int wd = t >> 6;
            wred[wd][0] = vs; wred[wd][1] = v1; wred[wd][2] = v2;
            wred[wd][3] = v4; wred[wd][4] = v8;
        }
        __syncthreads();
        if (t == 0) featA[bc] = (wred[0][0] + wred[1][0] + wred[2][0] + wred[3][0]) * (1.f / 4096.f);
        else if (t == 1) fm1[bc] = fmaxf(fmaxf(wred[0][1], wred[1][1]), fmaxf(wred[2][1], wred[3][1]));
        else if (t == 2) fm2[bc] = fmaxf(fmaxf(wred[0][2], wred[1][2]), fmaxf(wred[2][2], wred[3][2]));
        else if (t == 3) fm4[bc] = fmaxf(fmaxf(wred[0][3], wred[1][3]), fmaxf(wred[2][3], wred[3][3]));
        else if (t == 4) fm8[bc] = fmaxf(fmaxf(wred[0][4], wred[1][4]), fmaxf(wred[2][4], wred[3][4]));
    }
}

// ---------------------------------------------------------------------------
// K3: spatial-gate input with fused channel-gate MLP (8 waves).
// ---------------------------------------------------------------------------
__global__ __launch_bounds__(512) void k3_comp(
    const float* __restrict__ x, const float* __restrict__ bm2,
    const float* __restrict__ bm4, const float* __restrict__ bm8,
    const float* __restrict__ featA, const float* __restrict__ fm1,
    const float* __restrict__ fm2, const float* __restrict__ fm4,
    const float* __restrict__ fm8,
    const float* __restrict__ W1, const float* __restrict__ b1,
    const float* __restrict__ W2, const float* __restrict__ b2,
    float* __restrict__ g, float* __restrict__ comp)
{
    __shared__ float sf[5][256];
    __shared__ float sh[5][16];
    __shared__ float hs[16];
    __shared__ float sg[256];
    __shared__ float rmx[8][64];
    __shared__ float rsm[8][64];
    const int b = blockIdx.x >> 6;
    const int t = threadIdx.x;
    if (t < 256) {
        sf[0][t] = featA[(b << 8) + t];
        sf[1][t] = fm1[(b << 8) + t];
        sf[2][t] = fm2[(b << 8) + t];
        sf[3][t] = fm4[(b << 8) + t];
        sf[4][t] = fm8[(b << 8) + t];
    }
    __syncthreads();
    if (t < 80) {
        int f = t / 16, j = t % 16;
        float a = b1[j];
        for (int c = 0; c < 256; c++) a += sf[f][c] * W1[c * 16 + j];
        sh[f][j] = fmaxf(a, 0.f);
    }
    __syncthreads();
    if (t < 16) hs[t] = 4.f * sh[0][t] + sh[1][t] + sh[2][t] + sh[3][t] + sh[4][t];
    __syncthreads();
    if (t < 256) {
        float a = 8.f * b2[t];
        for (int j = 0; j < 16; j++) a += hs[j] * W2[j * 256 + t];
        sg[t] = 1.f / (1.f + __expf(-a));
    }
    __syncthreads();
    if ((blockIdx.x & 63) == 0 && t < 256) g[(b << 8) + t] = sg[t];
    const int pix = ((blockIdx.x & 63) << 6) + (t & 63);
    const int wid = t >> 6;
    const int c0 = wid << 5;
    const int h = pix >> 6, w = pix & 63;
    const int i2 = ((h >> 1) << 5) + (w >> 1);
    const int i4 = ((h >> 2) << 4) + (w >> 2);
    const int i8 = ((h >> 3) << 3) + (w >> 3);
    const float* xb = x + ((size_t)b << 8) * 4096;
    const float* p2 = bm2 + ((size_t)b << 8) * 1024;
    const float* p4 = bm4 + ((size_t)b << 8) * 256;
    const float* p8 = bm8 + ((size_t)b << 8) * 64;
    float mx = -1e30f, sm = 0.f;
    for (int c = c0; c < c0 + 32; c++) {
        float gc = sg[c];
        float xv = xb[(size_t)c * 4096 + pix] * gc;
        float v2 = p2[c * 1024 + i2] * gc;
        float v4 = p4[c * 256 + i4] * gc;
        float v8 = p8[c * 64 + i8] * gc;
        mx = fmaxf(fmaxf(mx, xv), fmaxf(fmaxf(v2, v4), v8));
        sm += xv + v2 + v4 + v8;
    }
    rmx[wid][t & 63] = mx;
    rsm[wid][t & 63] = sm;
    __syncthreads();
    if (wid == 0) {
        int l = t;
        float m = rmx[0][l], s = rsm[0][l];
        #pragma unroll
        for (int wsrc = 1; wsrc < 8; wsrc++) {
            m = fmaxf(m, rmx[wsrc][l]);
            s += rsm[wsrc][l];
        }
        comp[((size_t)b * 2) * 4096 + pix] = m;
        comp[((size_t)b * 2 + 1) * 4096 + pix] = s * (1.f / 1024.f);
    }
}

// ---------------------------------------------------------------------------
// K4: 7x7 conv (2->1, pad 3, no bias) + BN(eval) + sigmoid. Grid 64 x 256thr.
// ---------------------------------------------------------------------------
__global__ __launch_bounds__(256) void k4_spgate(
    const float* __restrict__ comp, const float* __restrict__ Wsp,
    const float* __restrict__ bn_g, const float* __restrict__ bn_b,
    const float* __restrict__ bn_m, const float* __restrict__ bn_v,
    float* __restrict__ spg)
{
    __shared__ float w[98];
    const int t = threadIdx.x;
    for (int i = t; i < 98; i += 256) w[i] = Wsp[i];
    __syncthreads();
    const int pixg = blockIdx.x * 256 + t;
    const int b = pixg >> 12;
    const int pix = pixg & 4095;
    const int h = pix >> 6, wx = pix & 63;
    const float* c0 = comp + (size_t)b * 2 * 4096;
    float acc = 0.f;
    for (int ci = 0; ci < 2; ci++)
        for (int kh = 0; kh < 7; kh++) {
            int hh = h + kh - 3;
            if (hh < 0 || hh >= 64) continue;
            for (int kw = 0; kw < 7; kw++) {
                int wwp = wx + kw - 3;
                if (wwp < 0 || wwp >= 64) continue;
                acc += c0[ci * 4096 + hh * 64 + wwp] * w[ci * 49 + kh * 7 + kw];
            }
        }
    float sc = rsqrtf(bn_v[0] + 1e-5f) * bn_g[0];
    float sp = (acc - bn_m[0]) * sc + bn_b[0];
    spg[pixg] = 1.f / (1.f + __expf(-sp));
}

// ---------------------------------------------------------------------------
// K_X2TP: fused gate+transpose+pool2 (x2 buffer eliminated).
// ---------------------------------------------------------------------------
__global__ __launch_bounds__(256) void k_x2tp(
    const float* __restrict__ x, const float* __restrict__ g,
    const float* __restrict__ spg,
    unsigned short* __restrict__ x2T, float* __restrict__ bm2b)
{
    __shared__ float sx[128][68];
    __shared__ float gsh[64];
    __shared__ float ssh[128];
    const int b  = blockIdx.z;
    const int cb = blockIdx.y * 64;
    const int nb = blockIdx.x * 128;
    const int t  = threadIdx.x;
    if (t < 64) gsh[t] = g[(b << 8) + cb + t];
    else if (t < 192) ssh[t - 64] = spg[(size_t)b * 4096 + nb + (t - 64)];
    __syncthreads();
    const int nl = t & 127;
    const int ch = t >> 7;
    const float sp = ssh[nl];
    #pragma unroll
    for (int r = 0; r < 32; r++) {
        int cl = ch + 2 * r;
        float v = x[((size_t)(b * 256 + cb + cl)) * 4096 + nb + nl];
        sx[nl][cl] = v * (gsh[cl] * sp);
    }
    __syncthreads();
    #pragma unroll
    for (int pass = 0; pass < 8; pass++) {
        int nl2 = (t >> 4) + 16 * pass;
        int c4 = (t & 15) * 4;
        uint2 pk;
        pk.x = (unsigned)f2bf(sx[nl2][c4])     | ((unsigned)f2bf(sx[nl2][c4 + 1]) << 16);
        pk.y = (unsigned)f2bf(sx[nl2][c4 + 2]) | ((unsigned)f2bf(sx[nl2][c4 + 3]) << 16);
        *(uint2*)(x2T + ((size_t)(b * 4096 + nb + nl2)) * 256 + cb + c4) = pk;
    }
    #pragma unroll
    for (int i = 0; i < 8; i++) {
        int o = t + 256 * i;
        int c = o >> 5, w2 = o & 31;
        float v = 0.25f * (sx[2 * w2][c] + sx[2 * w2 + 1][c]
                         + sx[64 + 2 * w2][c] + sx[64 + 2 * w2 + 1][c]);
        bm2b[((size_t)(b * 256 + cb + c)) * 1024 + (nb >> 7) * 32 + w2] = v;
    }
}

// ---------------------------------------------------------------------------
// K6: fp32 projection GEMM for low-res P2/P4/P8 with ON-THE-FLY POOLING
// (former k_pool48 absorbed into B-staging; same fp32 expression trees ->
// bit-identical values; bm4b/bm8b buffers and the pool48 launch deleted).
// blockIdx.x 0..15 -> P2, 16..19 -> P4, 20 -> P8.
// ---------------------------------------------------------------------------
__global__ __launch_bounds__(256) void k6_gemm(
    const float* __restrict__ Wq, const float* __restrict__ Wk, const float* __restrict__ Wv,
    const float* __restrict__ bm2b,
    float* __restrict__ P2, float* __restrict__ P4, float* __restrict__ P8)
{
    __shared__ float At[32][68];
    __shared__ float Bt[32][64];
    const int bx = blockIdx.x;
    int col_off, ns, nb, scale;
    float* outp;
    if (bx < 16)      { col_off = 0;   ns = 1024; outp = P2; nb = bx;      scale = 0; }
    else if (bx < 20) { col_off = 256; ns = 256;  outp = P4; nb = bx - 16; scale = 1; }
    else              { col_off = 512; ns = 64;   outp = P8; nb = 0;       scale = 2; }
    const int b = blockIdx.z;
    const int o_base = blockIdx.y * 64;
    const int n_base = nb * 64;
    const int t = threadIdx.x;
    const int tn = t >> 4, tm = t & 15;
    const int lk = t & 31, lo8 = t >> 5;
    const int ln = t & 63, lk4 = t >> 6;
    float acc[4][4];
    #pragma unroll
    for (int i = 0; i < 4; i++)
        #pragma unroll
        for (int j = 0; j < 4; j++) acc[i][j] = 0.f;
    for (int k0 = 0; k0 < 256; k0 += 32) {
        __syncthreads();
        #pragma unroll
        for (int r = 0; r < 8; r++) {
            int o = o_base + lo8 + 8 * r;
            const float* wrow = (o < 32) ? (Wq + (size_t)o * 1024)
                              : (o < 64) ? (Wk + (size_t)(o - 32) * 1024)
                                         : (Wv + (size_t)(o - 64) * 1024);
            At[lk][lo8 + 8 * r] = wrow[col_off + k0 + lk];
        }
        #pragma unroll
        for (int r = 0; r < 8; r++) {
            int c = k0 + lk4 + 4 * r;
            const float* row = bm2b + ((size_t)b * 256 + c) * 1024;
            float v;
            if (scale == 0) {
                v = row[n_base + ln];
            } else if (scale == 1) {
                int i4 = n_base + ln;
                int p = 64 * (i4 >> 4) + 2 * (i4 & 15);
                v = 0.25f * (row[p] + row[p + 1] + row[p + 32] + row[p + 33]);
            } else {
                int i8 = ln;
                int q0 = 32 * (i8 >> 3) + 2 * (i8 & 7);
                #define S4_(j) (0.25f * (row[64 * ((j) >> 4) + 2 * ((j) & 15)] \
                                       + row[64 * ((j) >> 4) + 2 * ((j) & 15) + 1] \
                                       + row[64 * ((j) >> 4) + 2 * ((j) & 15) + 32] \
                                       + row[64 * ((j) >> 4) + 2 * ((j) & 15) + 33]))
                v = 0.25f * (S4_(q0) + S4_(q0 + 1) + S4_(q0 + 16) + S4_(q0 + 17));
                #undef S4_
            }
            Bt[lk4 + 4 * r][ln] = v;
        }
        __syncthreads();
        #pragma unroll
        for (int kk = 0; kk < 32; kk++) {
            float4 a = *(const float4*)&At[kk][4 * tn];
            float4 bb = *(const float4*)&Bt[kk][4 * tm];
            acc[0][0] += a.x * bb.x; acc[0][1] += a.x * bb.y; acc[0][2] += a.x * bb.z; acc[0][3] += a.x * bb.w;
            acc[1][0] += a.y * bb.x; acc[1][1] += a.y * bb.y; acc[1][2] += a.y * bb.z; acc[1][3] += a.y * bb.w;
            acc[2][0] += a.z * bb.x; acc[2][1] += a.z * bb.y; acc[2][2] += a.z * bb.z; acc[2][3] += a.z * bb.w;
            acc[3][0] += a.w * bb.x; acc[3][1] += a.w * bb.y; acc[3][2] += a.w * bb.z; acc[3][3] += a.w * bb.w;
        }
    }
    #pragma unroll
    for (int i = 0; i < 4; i++)
        #pragma unroll
        for (int j = 0; j < 4; j++)
            outp[((size_t)b * 320 + o_base + 4 * tn + i) * ns + n_base + 4 * tm + j] = acc[i][j];
}

// ---------------------------------------------------------------------------
// K6M: full-res projection via bf16 MFMA, XCD-PINNED 1-D grid 640.
// obase==0 blocks additionally emit per-token |q|, |k| norms.
// ---------------------------------------------------------------------------
__global__ __launch_bounds__(256) void k6m(
    const unsigned short* __restrict__ WB, const unsigned short* __restrict__ x2T,
    const float* __restrict__ bq, const float* __restrict__ bk, const float* __restrict__ bv,
    const float* __restrict__ P2, const float* __restrict__ P4, const float* __restrict__ P8,
    unsigned short* __restrict__ qT, unsigned short* __restrict__ kT,
    unsigned short* __restrict__ vC, float* __restrict__ qn, float* __restrict__ kn)
{
    const int bid = blockIdx.x;
    const int b = (bid >> 1) & 3;
    const int rest = ((bid >> 3) << 1) | (bid & 1);   // 0..159
    const int nb = (rest & 31) * 128;
    const int obase = (rest >> 5) * 64;
    const int t = threadIdx.x;
    const int w_ = t >> 6, lane = t & 63;
    const int quad = lane >> 4, l16 = lane & 15;
    const int nbase = nb + 32 * w_;
    f32x4 acc[4][2];
    #pragma unroll
    for (int ot = 0; ot < 4; ot++)
        #pragma unroll
        for (int nt = 0; nt < 2; nt++) { acc[ot][nt][0] = 0.f; acc[ot][nt][1] = 0.f; acc[ot][nt][2] = 0.f; acc[ot][nt][3] = 0.f; }
    const unsigned short* xb = x2T + ((size_t)b * 4096 + nbase) * 256;
    for (int k0 = 0; k0 < 256; k0 += 32) {
        FRAG af[4], bf[2];
        #pragma unroll
        for (int ot = 0; ot < 4; ot++)
            af[ot].u = *(const uint4*)(WB + (size_t)(obase + 16 * ot + l16) * 256 + k0 + quad * 8);
        #pragma unroll
        for (int nt = 0; nt < 2; nt++)
            bf[nt].u = *(const uint4*)(xb + (size_t)(16 * nt + l16) * 256 + k0 + quad * 8);
        #pragma unroll
        for (int ot = 0; ot < 4; ot++)
            #pragma unroll
            for (int nt = 0; nt < 2; nt++)
                acc[ot][nt] = __builtin_amdgcn_mfma_f32_16x16x32_bf16(af[ot].s, bf[nt].s, acc[ot][nt], 0, 0, 0);
    }
    float qsq[2] = {0.f, 0.f}, ksq[2] = {0.f, 0.f};
    #pragma unroll
    for (int ot = 0; ot < 4; ot++) {
        #pragma unroll
        for (int nt = 0; nt < 2; nt++) {
            int n = nbase + 16 * nt + l16;
            int h = n >> 6, wx = n & 63;
            int i2 = ((h >> 1) << 5) + (wx >> 1);
            int i4 = ((h >> 2) << 4) + (wx >> 2);
            int i8 = ((h >> 3) << 3) + (wx >> 3);
            float vals[4];
            #pragma unroll
            for (int r = 0; r < 4; r++) {
                int o = obase + 16 * ot + 4 * quad + r;
                float bias = (o < 32) ? bq[o] : (o < 64) ? bk[o - 32] : bv[o - 64];
                size_t ro = (size_t)b * 320 + o;
                vals[r] = acc[ot][nt][r] + bias
                        + P2[ro * 1024 + i2] + P4[ro * 256 + i4] + P8[ro * 64 + i8];
            }
            float ss = vals[0] * vals[0] + vals[1] * vals[1]
                     + vals[2] * vals[2] + vals[3] * vals[3];
            if (ot < 2) qsq[nt] += ss; else ksq[nt] += ss;
            int o0 = obase + 16 * ot + 4 * quad;
            if (o0 < 64) {
                uint2 pk;
                pk.x = (unsigned)f2bf(vals[0]) | ((unsigned)f2bf(vals[1]) << 16);
                pk.y = (unsigned)f2bf(vals[2]) | ((unsigned)f2bf(vals[3]) << 16);
                if (o0 < 32)
                    *(uint2*)(qT + ((size_t)(b * 4096 + n)) * 32 + o0) = pk;
                else
                    *(uint2*)(kT + ((size_t)(b * 4096 + n)) * 32 + (o0 - 32)) = pk;
            } else {
                int chunk = n >> 6;
                int kk = n & 63;
                int khw_ = (kk >> 5) & 1, qd = (kk >> 3) & 3, ko = kk & 7;
                unsigned short* dst = vC + (((size_t)b * 64 + chunk) << 14);
                #pragma unroll
                for (int r = 0; r < 4; r++) {
                    int c = o0 - 64 + r;
                    dst[((((c >> 4) << 1) + khw_) << 9) + ((qd * 16 + (c & 15)) << 3) + ko] = f2bf(vals[r]);
                }
            }
        }
    }
    if (obase == 0) {
        #pragma unroll
        for (int nt = 0; nt < 2; nt++) {
            float q2 = qsq[nt], k2 = ksq[nt];
            q2 += __shfl_xor(q2, 16); q2 += __shfl_xor(q2, 32);
            k2 += __shfl_xor(k2, 16); k2 += __shfl_xor(k2, 32);
            if (quad == 0) {
                int n = nbase + 16 * nt + l16;
                qn[b * 4096 + n] = sqrtf(q2);
                kn[b * 4096 + n] = sqrtf(k2);
            }
        }
    }
}

// ---------------------------------------------------------------------------
// K7B v19 = v18 + IN-BLOCK softmax shift bound (k_mbound fused): each block
// cooperatively reduces max_n |k_n| over its b (16 KB kn, L2-resident,
// XCD-pinned), then mN = qn[nq] * (1.02 * K). Same fp32 expression as the
// deleted k_mbound kernel; softmax is shift-exact for any bound >= max.
// Denominator still self-computed (l accumulation).
// ---------------------------------------------------------------------------
__global__ __launch_bounds__(512) void k7b_attn(
    const unsigned short* __restrict__ qT, const unsigned short* __restrict__ kT,
    const unsigned short* __restrict__ vC, const float* __restrict__ qn,
    const float* __restrict__ kn, const float* __restrict__ x,
    const float* __restrict__ g, const float* __restrict__ spg,
    const float* __restrict__ gamma, float* __restrict__ outp)
{
    __shared__ __align__(16) unsigned short PL[2][64][64];  // 16 KB swizzled P
    __shared__ float SB[128][68];                           // 34.8 KB combine buffer
    __shared__ float gsh[256];
    __shared__ float ssh[64];
    __shared__ float lsh[2][64];
    __shared__ float ilsh[64];
    __shared__ float redk[8];
    const int bid = blockIdx.x;
    const int b = (bid >> 1) & 3;
    const int qbase = (((bid >> 3) << 1) | (bid & 1)) << 6;
    const int t = threadIdx.x;
    const int wid = t >> 6, lane = t & 63;
    const int cw = wid & 3, khw = wid >> 2;
    const int quad = lane >> 4, l16 = lane & 15;
    const int ntq = wid & 3;                // QK n-tile of this wave
    const int mt0 = 2 * khw, mt1 = 2 * khw + 1;
    const int nq = qbase + 16 * ntq + l16;  // column of this wave's P rows

    FRAG qf;
    qf.u = *(const uint4*)(qT + ((size_t)(b * 4096 + nq)) * 32 + quad * 8);

    // --- fused k_mbound: K = max_n |k_n| over this b, block-wide reduce ---
    {
        float kmx = 0.f;
        #pragma unroll
        for (int i = 0; i < 8; i++)
            kmx = fmaxf(kmx, kn[b * 4096 + t + 512 * i]);
        #pragma unroll
        for (int o = 1; o < 64; o <<= 1) kmx = fmaxf(kmx, __shfl_xor(kmx, o));
        if (lane == 0) redk[wid] = kmx;
    }
    __syncthreads();
    const float Kb = fmaxf(fmaxf(fmaxf(redk[0], redk[1]), fmaxf(redk[2], redk[3])),
                           fmaxf(fmaxf(redk[4], redk[5]), fmaxf(redk[6], redk[7])));
    const float mN = qn[b * 4096 + nq] * (1.02f * Kb);
    float l_run = 0.f;

    f32x4 acc[4][4];
    #pragma unroll
    for (int ct = 0; ct < 4; ct++)
        #pragma unroll
        for (int nt = 0; nt < 4; nt++) { acc[ct][nt][0] = 0.f; acc[ct][nt][1] = 0.f; acc[ct][nt][2] = 0.f; acc[ct][nt][3] = 0.f; }
    const unsigned short* kTb = kT + (size_t)b * 4096 * 32;
    const unsigned short* vfb = vC + ((size_t)b * 64 << 14)
                              + (((8 * cw) + khw) << 9) + lane * 8;

    const int po  = 4 * (quad & 1);
    const int pg0 = ((4 * khw + (quad >> 1)) ^ (l16 & 7));
    const int pg1 = ((4 * khw + 2 + (quad >> 1)) ^ (l16 & 7));
    const int pgr = ((4 * khw + quad) ^ (l16 & 7)) << 3;

    FRAG avA[4], avB[4], kc0, kc1;

#define AV_LOAD(AV, CH) do { \
    const unsigned short* vfj = vfb + ((size_t)(CH) << 14); \
    AV[0].u = *(const uint4*)(vfj); \
    AV[1].u = *(const uint4*)(vfj + 1024); \
    AV[2].u = *(const uint4*)(vfj + 2048); \
    AV[3].u = *(const uint4*)(vfj + 3072); \
} while (0)

#define KC_LOAD(CH) do { \
    const int mo_ = (CH) << 6; \
    kc0.u = *(const uint4*)(kTb + (size_t)(mo_ + 16 * mt0 + l16) * 32 + quad * 8); \
    kc1.u = *(const uint4*)(kTb + (size_t)(mo_ + 16 * mt1 + l16) * 32 + quad * 8); \
} while (0)

#define QK_EXP_STORE(DST) do { \
    f32x4 z; z[0] = 0.f; z[1] = 0.f; z[2] = 0.f; z[3] = 0.f; \
    f32x4 e0 = __builtin_amdgcn_mfma_f32_16x16x32_bf16(kc0.s, qf.s, z, 0, 0, 0); \
    f32x4 e1 = __builtin_amdgcn_mfma_f32_16x16x32_bf16(kc1.s, qf.s, z, 0, 0, 0); \
    union { float f; unsigned int u; } p0, p1, p2, p3; \
    uint2 pkA, pkB; \
    p0.f = __expf(e0[0] - mN); p1.f = __expf(e0[1] - mN); \
    p2.f = __expf(e0[2] - mN); p3.f = __expf(e0[3] - mN); \
    l_run += (p0.f + p1.f) + (p2.f + p3.f); \
    pkA.x = __builtin_amdgcn_perm(p1.u, p0.u, 0x07060302u); \
    pkA.y = __builtin_amdgcn_perm(p3.u, p2.u, 0x07060302u); \
    p0.f = __expf(e1[0] - mN); p1.f = __expf(e1[1] - mN); \
    p2.f = __expf(e1[2] - mN); p3.f = __expf(e1[3] - mN); \
    l_run += (p0.f + p1.f) + (p2.f + p3.f); \
    pkB.x = __builtin_amdgcn_perm(p1.u, p0.u, 0x07060302u); \
    pkB.y = __builtin_amdgcn_perm(p3.u, p2.u, 0x07060302u); \
    *(uint2*)&PL[DST][16 * ntq + l16][(pg0 << 3) + po] = pkA; \
    *(uint2*)&PL[DST][16 * ntq + l16][(pg1 << 3) + po] = pkB; \
} while (0)

#define PV_STEP(AV, CUR) do { \
    FRAG bp[4]; \
    _Pragma("unroll") \
    for (int nt = 0; nt < 4; nt++) \
        bp[nt].u = *(const uint4*)&PL[CUR][16 * nt + l16][pgr]; \
    __builtin_amdgcn_s_setprio(1); \
    _Pragma("unroll") \
    for (int ct = 0; ct < 4; ct++) { \
        _Pragma("unroll") \
        for (int nt = 0; nt < 4; nt++) \
            acc[ct][nt] = __builtin_amdgcn_mfma_f32_16x16x32_bf16(AV[ct].s, bp[nt].s, acc[ct][nt], 0, 0, 0); \
    } \
    __builtin_amdgcn_s_setprio(0); \
} while (0)

    // --- prologue: av(0); QK(0)->PL[0]; kc for chunk 1 ---
    AV_LOAD(avA, 0);
    KC_LOAD(0);
    QK_EXP_STORE(0);
    KC_LOAD(1);

    for (int jj = 0; jj < 32; jj++) {
        const int j = 2 * jj;
        __syncthreads();
        {
            AV_LOAD(avB, j + 1);
            QK_EXP_STORE(1);
            if (j < 62) KC_LOAD(j + 2);
        }
        PV_STEP(avA, 0);
        __syncthreads();
        if (j < 62) {
            AV_LOAD(avA, j + 2);
            QK_EXP_STORE(0);
            if (j < 61) KC_LOAD(j + 3);
        }
        PV_STEP(avB, 1);
    }
#undef AV_LOAD
#undef KC_LOAD
#undef QK_EXP_STORE
#undef PV_STEP

    // l: reduce across quads -> per-(ntq,l16) half-sum.
    l_run += __shfl_xor(l_run, 16);
    l_run += __shfl_xor(l_run, 32);
    if (quad == 0) lsh[khw][16 * ntq + l16] = l_run;

    // residual gate factors for the epilogue
    if (t < 256) gsh[t] = g[(b << 8) + t];
    else if (t < 320) ssh[t - 256] = spg[(size_t)b * 4096 + qbase + (t - 256)];

    // --- epilogue: combine khw halves via SB, 2 c-stripe rounds ---
    const float gm = gamma[0];
    for (int s = 0; s < 2; s++) {
        __syncthreads();
        if (s == 0 && t < 64) ilsh[t] = 1.f / (lsh[0][t] + lsh[1][t]);
        if (khw == 0 && (cw >> 1) == s) {
            #pragma unroll
            for (int ct = 0; ct < 4; ct++)
                #pragma unroll
                for (int nt = 0; nt < 4; nt++)
                    #pragma unroll
                    for (int r = 0; r < 4; r++)
                        SB[64 * (cw & 1) + 16 * ct + 4 * quad + r][16 * nt + l16] = acc[ct][nt][r];
        }
        __syncthreads();
        if (khw == 1 && (cw >> 1) == s) {
            #pragma unroll
            for (int ct = 0; ct < 4; ct++)
                #pragma unroll
                for (int nt = 0; nt < 4; nt++)
                    #pragma unroll
                    for (int r = 0; r < 4; r++)
                        SB[64 * (cw & 1) + 16 * ct + 4 * quad + r][16 * nt + l16] += acc[ct][nt][r];
        }
        __syncthreads();
        // cooperative store: 128c x 64n
        #pragma unroll
        for (int pass = 0; pass < 4; pass++) {
            int cl = (t >> 4) + 32 * pass;
            int n4 = (t & 15) * 4;
            float4 vv = *(float4*)&SB[cl][n4];
            float4 il4 = *(float4*)&ilsh[n4];
            size_t idx = ((size_t)(b * 256 + 128 * s + cl)) * 4096 + qbase + n4;
            float4 xv = *(const float4*)(x + idx);
            float gc = gsh[128 * s + cl];
            float4 ss4 = *(float4*)&ssh[n4];
            float4 ov;
            ov.x = gm * vv.x * il4.x + xv.x * (gc * ss4.x);
            ov.y = gm * vv.y * il4.y + xv.y * (gc * ss4.y);
            ov.z = gm * vv.z * il4.z + xv.z * (gc * ss4.z);
            ov.w = gm * vv.w * il4.w + xv.w * (gc * ss4.w);
            *(float4*)(outp + idx) = ov;
        }
    }
}

// ---------------------------------------------------------------------------
extern "C" void kernel_launch(void* const* d_in, const int* in_sizes, int n_in,
                              void* d_out, int out_size, void* d_ws, size_t ws_size,
                              hipStream_t stream) {
    (void)in_sizes; (void)n_in; (void)out_size; (void)ws_size;
    const float* x    = (const float*)d_in[0];
    const float* W1   = (const float*)d_in[1];
    const float* b1   = (const float*)d_in[2];
    const float* W2   = (const float*)d_in[3];
    const float* b2   = (const float*)d_in[4];
    const float* Wq   = (const float*)d_in[5];
    const float* bq   = (const float*)d_in[6];
    const float* Wk   = (const float*)d_in[7];
    const float* bk   = (const float*)d_in[8];
    const float* Wv   = (const float*)d_in[9];
    const float* bv   = (const float*)d_in[10];
    const float* gam  = (const float*)d_in[11];
    const float* Wsp  = (const float*)d_in[12];
    const float* bn_g = (const float*)d_in[13];
    const float* bn_b = (const float*)d_in[14];
    const float* bn_m = (const float*)d_in[15];
    const float* bn_v = (const float*)d_in[16];

    float* ws = (float*)d_ws;
    float* bm2   = ws; ws += (size_t)4 * 256 * 1024;
    float* bm4   = ws; ws += (size_t)4 * 256 * 256;
    float* bm8   = ws; ws += (size_t)4 * 256 * 64;
    float* featA = ws; ws += 1024;
    float* fm1   = ws; ws += 1024;
    float* fm2   = ws; ws += 1024;
    float* fm4   = ws; ws += 1024;
    float* fm8   = ws; ws += 1024;
    float* g     = ws; ws += 1024;
    float* comp  = ws; ws += (size_t)4 * 2 * 4096;
    float* spg   = ws; ws += (size_t)4 * 4096;
    float* bm2b  = ws; ws += (size_t)4 * 256 * 1024;
    float* P2    = ws; ws += (size_t)4 * 320 * 1024;
    float* P4    = ws; ws += (size_t)4 * 320 * 256;
    float* P8    = ws; ws += (size_t)4 * 320 * 64;
    float* qn    = ws; ws += (size_t)4 * 4096;
    float* kn    = ws; ws += (size_t)4 * 4096;
    unsigned short* qT  = (unsigned short*)ws; ws += (size_t)4 * 4096 * 32 / 2;
    unsigned short* kT  = (unsigned short*)ws; ws += (size_t)4 * 4096 * 32 / 2;
    unsigned short* vCp = (unsigned short*)ws; ws += (size_t)4 * 64 * 16384 / 2;
    unsigned short* x2T = (unsigned short*)ws; ws += (size_t)4 * 4096 * 256 / 2;
    unsigned short* WB  = (unsigned short*)ws; ws += (size_t)320 * 256 / 2;

    // Stage 1: channel gate (pyramid + fused weight-cast)
    k_pyramid<<<1104, 256, 0, stream>>>(x, bm2, bm4, bm8,
                                        featA, fm1, fm2, fm4, fm8,
                                        Wq, Wk, Wv, WB);
    // Stage 2: spatial gate (k3 with fused channel-gate MLP; 8 waves)
    k3_comp<<<256, 512, 0, stream>>>(x, bm2, bm4, bm8,
                                     featA, fm1, fm2, fm4, fm8,
                                     W1, b1, W2, b2, g, comp);
    k4_spgate<<<64, 256, 0, stream>>>(comp, Wsp, bn_g, bn_b, bn_m, bn_v, spg);
    // Fused gate+transpose+pool2 (bm2b only; deeper pools now on-the-fly)
    k_x2tp<<<dim3(32, 4, 4), 256, 0, stream>>>(x, g, spg, x2T, bm2b);
    // Stage 3: q/k/v projections (low-res GEMM pools bm4/bm8 on the fly)
    k6_gemm<<<dim3(21, 5, 4), 256, 0, stream>>>(Wq, Wk, Wv, bm2b, P2, P4, P8);
    k6m<<<640, 256, 0, stream>>>(WB, x2T, bq, bk, bv, P2, P4, P8, qT, kT, vCp, qn, kn);
    // Attention: single pass; shift bound + denominator computed in-kernel
    k7b_attn<<<256, 512, 0, stream>>>(qT, kT, vCp, qn, kn, x, g, spg, gam, (float*)d_out);
}

// Round 13
// 235.789 us; speedup vs baseline: 1.0514x; 1.0514x over previous
//
#include <hip/hip_runtime.h>
#include <math.h>

// Shapes (fixed): B=4, C=256, H=W=64, N=4096, 4C=1024, c8=32, r=16.

typedef float f32x4 __attribute__((ext_vector_type(4)));
typedef short s16x8 __attribute__((ext_vector_type(8)));
union FRAG { uint4 u; s16x8 s; };

__device__ __forceinline__ unsigned short f2bf(float f) {
    union { float f; unsigned int u; } v; v.f = f;
    unsigned int r = v.u + 0x7FFFu + ((v.u >> 16) & 1u);
    return (unsigned short)(r >> 16);
}

// ---------------------------------------------------------------------------
// K1: per-(b,c) plane -> block-mean pyramid + feats.
// Carries 80 extra blocks (bc >= 1024) doing the WB bf16 weight-cast.
// ---------------------------------------------------------------------------
__global__ __launch_bounds__(256) void k_pyramid(
    const float* __restrict__ xin,
    float* __restrict__ bm2, float* __restrict__ bm4, float* __restrict__ bm8,
    float* __restrict__ featA, float* __restrict__ fm1, float* __restrict__ fm2,
    float* __restrict__ fm4, float* __restrict__ fm8,
    const float* __restrict__ Wq, const float* __restrict__ Wk,
    const float* __restrict__ Wv, unsigned short* __restrict__ WB)
{
    __shared__ float sx[4096];
    __shared__ float s2[1024];
    __shared__ float s4[256];
    __shared__ float wred[4][8];
    const int bc = blockIdx.x;
    const int t = threadIdx.x;
    if (bc >= 1024) {
        const int e0 = (bc - 1024) * 1024 + t * 4;
        const int o = e0 >> 8, col = e0 & 255;
        const float* row = (o < 32) ? (Wq + (size_t)o * 1024)
                          : (o < 64) ? (Wk + (size_t)(o - 32) * 1024)
                                     : (Wv + (size_t)(o - 64) * 1024);
        float4 v = *(const float4*)(row + 768 + col);
        uint2 pk;
        pk.x = (unsigned)f2bf(v.x) | ((unsigned)f2bf(v.y) << 16);
        pk.y = (unsigned)f2bf(v.z) | ((unsigned)f2bf(v.w) << 16);
        *(uint2*)(WB + e0) = pk;
        return;
    }
    const float* xp = xin + (size_t)bc * 4096;
    float sum = 0.f, mx = -1e30f;
    for (int r = 0; r < 4; r++) {
        int i4 = t + 256 * r;
        float4 v = ((const float4*)xp)[i4];
        sum += v.x + v.y + v.z + v.w;
        mx = fmaxf(mx, fmaxf(fmaxf(v.x, v.y), fmaxf(v.z, v.w)));
        ((float4*)sx)[i4] = v;
    }
    __syncthreads();
    float mx2 = -1e30f;
    for (int r = 0; r < 4; r++) {
        int i = t + 256 * r;
        int r2 = i >> 5, c2 = i & 31;
        int p0 = 128 * r2 + 2 * c2;
        float v = 0.25f * (sx[p0] + sx[p0 + 1] + sx[p0 + 64] + sx[p0 + 65]);
        s2[i] = v;
        bm2[(size_t)bc * 1024 + i] = v;
        mx2 = fmaxf(mx2, v);
    }
    __syncthreads();
    float mx4;
    {
        int r4 = t >> 4, c4 = t & 15;
        int p0 = 64 * r4 + 2 * c4;
        float v = 0.25f * (s2[p0] + s2[p0 + 1] + s2[p0 + 32] + s2[p0 + 33]);
        s4[t] = v;
        bm4[(size_t)bc * 256 + t] = v;
        mx4 = v;
    }
    __syncthreads();
    float mx8 = -1e30f;
    if (t < 64) {
        int r8 = t >> 3, c8 = t & 7;
        int p0 = 32 * r8 + 2 * c8;
        float v = 0.25f * (s4[p0] + s4[p0 + 1] + s4[p0 + 16] + s4[p0 + 17]);
        bm8[(size_t)bc * 64 + t] = v;
        mx8 = v;
    }
    {
        float vs = sum, v1 = mx, v2 = mx2, v4 = mx4, v8 = mx8;
        #pragma unroll
        for (int o = 1; o < 64; o <<= 1) {
            vs += __shfl_xor(vs, o);
            v1 = fmaxf(v1, __shfl_xor(v1, o));
            v2 = fmaxf(v2, __shfl_xor(v2, o));
            v4 = fmaxf(v4, __shfl_xor(v4, o));
            v8 = fmaxf(v8, __shfl_xor(v8, o));
        }
        if ((t & 63) == 0) {
            int wd = t >> 6;
            wred[wd][0] = vs; wred[wd][1] = v1; wred[wd][2] = v2;
            wred[wd][3] = v4; wred[wd][4] = v8;
        }
        __syncthreads();
        if (t == 0) featA[bc] = (wred[0][0] + wred[1][0] + wred[2][0] + wred[3][0]) * (1.f / 4096.f);
        else if (t == 1) fm1[bc] = fmaxf(fmaxf(wred[0][1], wred[1][1]), fmaxf(wred[2][1], wred[3][1]));
        else if (t == 2) fm2[bc] = fmaxf(fmaxf(wred[0][2], wred[1][2]), fmaxf(wred[2][2], wred[3][2]));
        else if (t == 3) fm4[bc] = fmaxf(fmaxf(wred[0][3], wred[1][3]), fmaxf(wred[2][3], wred[3][3]));
        else if (t == 4) fm8[bc] = fmaxf(fmaxf(wred[0][4], wred[1][4]), fmaxf(wred[2][4], wred[3][4]));
    }
}

// ---------------------------------------------------------------------------
// K3: spatial-gate input with fused channel-gate MLP (8 waves).
// ---------------------------------------------------------------------------
__global__ __launch_bounds__(512) void k3_comp(
    const float* __restrict__ x, const float* __restrict__ bm2,
    const float* __restrict__ bm4, const float* __restrict__ bm8,
    const float* __restrict__ featA, const float* __restrict__ fm1,
    const float* __restrict__ fm2, const float* __restrict__ fm4,
    const float* __restrict__ fm8,
    const float* __restrict__ W1, const float* __restrict__ b1,
    const float* __restrict__ W2, const float* __restrict__ b2,
    float* __restrict__ g, float* __restrict__ comp)
{
    __shared__ float sf[5][256];
    __shared__ float sh[5][16];
    __shared__ float hs[16];
    __shared__ float sg[256];
    __shared__ float rmx[8][64];
    __shared__ float rsm[8][64];
    const int b = blockIdx.x >> 6;
    const int t = threadIdx.x;
    if (t < 256) {
        sf[0][t] = featA[(b << 8) + t];
        sf[1][t] = fm1[(b << 8) + t];
        sf[2][t] = fm2[(b << 8) + t];
        sf[3][t] = fm4[(b << 8) + t];
        sf[4][t] = fm8[(b << 8) + t];
    }
    __syncthreads();
    if (t < 80) {
        int f = t / 16, j = t % 16;
        float a = b1[j];
        for (int c = 0; c < 256; c++) a += sf[f][c] * W1[c * 16 + j];
        sh[f][j] = fmaxf(a, 0.f);
    }
    __syncthreads();
    if (t < 16) hs[t] = 4.f * sh[0][t] + sh[1][t] + sh[2][t] + sh[3][t] + sh[4][t];
    __syncthreads();
    if (t < 256) {
        float a = 8.f * b2[t];
        for (int j = 0; j < 16; j++) a += hs[j] * W2[j * 256 + t];
        sg[t] = 1.f / (1.f + __expf(-a));
    }
    __syncthreads();
    if ((blockIdx.x & 63) == 0 && t < 256) g[(b << 8) + t] = sg[t];
    const int pix = ((blockIdx.x & 63) << 6) + (t & 63);
    const int wid = t >> 6;
    const int c0 = wid << 5;
    const int h = pix >> 6, w = pix & 63;
    const int i2 = ((h >> 1) << 5) + (w >> 1);
    const int i4 = ((h >> 2) << 4) + (w >> 2);
    const int i8 = ((h >> 3) << 3) + (w >> 3);
    const float* xb = x + ((size_t)b << 8) * 4096;
    const float* p2 = bm2 + ((size_t)b << 8) * 1024;
    const float* p4 = bm4 + ((size_t)b << 8) * 256;
    const float* p8 = bm8 + ((size_t)b << 8) * 64;
    float mx = -1e30f, sm = 0.f;
    for (int c = c0; c < c0 + 32; c++) {
        float gc = sg[c];
        float xv = xb[(size_t)c * 4096 + pix] * gc;
        float v2 = p2[c * 1024 + i2] * gc;
        float v4 = p4[c * 256 + i4] * gc;
        float v8 = p8[c * 64 + i8] * gc;
        mx = fmaxf(fmaxf(mx, xv), fmaxf(fmaxf(v2, v4), v8));
        sm += xv + v2 + v4 + v8;
    }
    rmx[wid][t & 63] = mx;
    rsm[wid][t & 63] = sm;
    __syncthreads();
    if (wid == 0) {
        int l = t;
        float m = rmx[0][l], s = rsm[0][l];
        #pragma unroll
        for (int wsrc = 1; wsrc < 8; wsrc++) {
            m = fmaxf(m, rmx[wsrc][l]);
            s += rsm[wsrc][l];
        }
        comp[((size_t)b * 2) * 4096 + pix] = m;
        comp[((size_t)b * 2 + 1) * 4096 + pix] = s * (1.f / 1024.f);
    }
}

// ---------------------------------------------------------------------------
// K4: 7x7 conv (2->1, pad 3, no bias) + BN(eval) + sigmoid. Grid 64 x 256thr.
// ---------------------------------------------------------------------------
__global__ __launch_bounds__(256) void k4_spgate(
    const float* __restrict__ comp, const float* __restrict__ Wsp,
    const float* __restrict__ bn_g, const float* __restrict__ bn_b,
    const float* __restrict__ bn_m, const float* __restrict__ bn_v,
    float* __restrict__ spg)
{
    __shared__ float w[98];
    const int t = threadIdx.x;
    for (int i = t; i < 98; i += 256) w[i] = Wsp[i];
    __syncthreads();
    const int pixg = blockIdx.x * 256 + t;
    const int b = pixg >> 12;
    const int pix = pixg & 4095;
    const int h = pix >> 6, wx = pix & 63;
    const float* c0 = comp + (size_t)b * 2 * 4096;
    float acc = 0.f;
    for (int ci = 0; ci < 2; ci++)
        for (int kh = 0; kh < 7; kh++) {
            int hh = h + kh - 3;
            if (hh < 0 || hh >= 64) continue;
            for (int kw = 0; kw < 7; kw++) {
                int wwp = wx + kw - 3;
                if (wwp < 0 || wwp >= 64) continue;
                acc += c0[ci * 4096 + hh * 64 + wwp] * w[ci * 49 + kh * 7 + kw];
            }
        }
    float sc = rsqrtf(bn_v[0] + 1e-5f) * bn_g[0];
    float sp = (acc - bn_m[0]) * sc + bn_b[0];
    spg[pixg] = 1.f / (1.f + __expf(-sp));
}

// ---------------------------------------------------------------------------
// K_X2TP: fused gate+transpose+pool2 (x2 buffer eliminated).
// ---------------------------------------------------------------------------
__global__ __launch_bounds__(256) void k_x2tp(
    const float* __restrict__ x, const float* __restrict__ g,
    const float* __restrict__ spg,
    unsigned short* __restrict__ x2T, float* __restrict__ bm2b)
{
    __shared__ float sx[128][68];
    __shared__ float gsh[64];
    __shared__ float ssh[128];
    const int b  = blockIdx.z;
    const int cb = blockIdx.y * 64;
    const int nb = blockIdx.x * 128;
    const int t  = threadIdx.x;
    if (t < 64) gsh[t] = g[(b << 8) + cb + t];
    else if (t < 192) ssh[t - 64] = spg[(size_t)b * 4096 + nb + (t - 64)];
    __syncthreads();
    const int nl = t & 127;
    const int ch = t >> 7;
    const float sp = ssh[nl];
    #pragma unroll
    for (int r = 0; r < 32; r++) {
        int cl = ch + 2 * r;
        float v = x[((size_t)(b * 256 + cb + cl)) * 4096 + nb + nl];
        sx[nl][cl] = v * (gsh[cl] * sp);
    }
    __syncthreads();
    #pragma unroll
    for (int pass = 0; pass < 8; pass++) {
        int nl2 = (t >> 4) + 16 * pass;
        int c4 = (t & 15) * 4;
        uint2 pk;
        pk.x = (unsigned)f2bf(sx[nl2][c4])     | ((unsigned)f2bf(sx[nl2][c4 + 1]) << 16);
        pk.y = (unsigned)f2bf(sx[nl2][c4 + 2]) | ((unsigned)f2bf(sx[nl2][c4 + 3]) << 16);
        *(uint2*)(x2T + ((size_t)(b * 4096 + nb + nl2)) * 256 + cb + c4) = pk;
    }
    #pragma unroll
    for (int i = 0; i < 8; i++) {
        int o = t + 256 * i;
        int c = o >> 5, w2 = o & 31;
        float v = 0.25f * (sx[2 * w2][c] + sx[2 * w2 + 1][c]
                         + sx[64 + 2 * w2][c] + sx[64 + 2 * w2 + 1][c]);
        bm2b[((size_t)(b * 256 + cb + c)) * 1024 + (nb >> 7) * 32 + w2] = v;
    }
}

// ---------------------------------------------------------------------------
// K_POOL48: bm2b -> bm4b, bm8b (restored — the on-the-fly pooling fusion in
// k6_gemm regressed ~10 µs in round 12: 4-16 strided loads per staged
// element on the critical path vs this trivial 1024-block streamer).
// ---------------------------------------------------------------------------
__global__ __launch_bounds__(256) void k_pool48(
    const float* __restrict__ bm2b, float* __restrict__ bm4b, float* __restrict__ bm8b)
{
    __shared__ float s2[1024];
    __shared__ float s4[256];
    const int bc = blockIdx.x;
    const int t = threadIdx.x;
    ((float4*)s2)[t] = ((const float4*)(bm2b + (size_t)bc * 1024))[t];
    __syncthreads();
    {
        int r4 = t >> 4, c4 = t & 15;
        int p0 = 64 * r4 + 2 * c4;
        float v = 0.25f * (s2[p0] + s2[p0 + 1] + s2[p0 + 32] + s2[p0 + 33]);
        s4[t] = v;
        bm4b[(size_t)bc * 256 + t] = v;
    }
    __syncthreads();
    if (t < 64) {
        int r8 = t >> 3, c8 = t & 7;
        int p0 = 32 * r8 + 2 * c8;
        bm8b[(size_t)bc * 64 + t] = 0.25f * (s4[p0] + s4[p0 + 1] + s4[p0 + 16] + s4[p0 + 17]);
    }
}

// ---------------------------------------------------------------------------
// K6: fp32 projection GEMM for low-res P2/P4/P8 (round-11 proven version).
// ---------------------------------------------------------------------------
__global__ __launch_bounds__(256) void k6_gemm(
    const float* __restrict__ Wq, const float* __restrict__ Wk, const float* __restrict__ Wv,
    const float* __restrict__ bm2b, const float* __restrict__ bm4b, const float* __restrict__ bm8b,
    float* __restrict__ P2, float* __restrict__ P4, float* __restrict__ P8)
{
    __shared__ float At[32][68];
    __shared__ float Bt[32][64];
    const int bx = blockIdx.x;
    int col_off, ns, nb;
    const float* src;
    float* outp;
    if (bx < 16)      { col_off = 0;   src = bm2b; ns = 1024; outp = P2; nb = bx; }
    else if (bx < 20) { col_off = 256; src = bm4b; ns = 256;  outp = P4; nb = bx - 16; }
    else              { col_off = 512; src = bm8b; ns = 64;   outp = P8; nb = 0; }
    const int b = blockIdx.z;
    const int o_base = blockIdx.y * 64;
    const int n_base = nb * 64;
    const int t = threadIdx.x;
    const int tn = t >> 4, tm = t & 15;
    const int lk = t & 31, lo8 = t >> 5;
    const int ln = t & 63, lk4 = t >> 6;
    float acc[4][4];
    #pragma unroll
    for (int i = 0; i < 4; i++)
        #pragma unroll
        for (int j = 0; j < 4; j++) acc[i][j] = 0.f;
    for (int k0 = 0; k0 < 256; k0 += 32) {
        __syncthreads();
        #pragma unroll
        for (int r = 0; r < 8; r++) {
            int o = o_base + lo8 + 8 * r;
            const float* wrow = (o < 32) ? (Wq + (size_t)o * 1024)
                              : (o < 64) ? (Wk + (size_t)(o - 32) * 1024)
                                         : (Wv + (size_t)(o - 64) * 1024);
            At[lk][lo8 + 8 * r] = wrow[col_off + k0 + lk];
        }
        #pragma unroll
        for (int r = 0; r < 8; r++)
            Bt[lk4 + 4 * r][ln] = src[((size_t)b * 256 + k0 + lk4 + 4 * r) * ns + n_base + ln];
        __syncthreads();
        #pragma unroll
        for (int kk = 0; kk < 32; kk++) {
            float4 a = *(const float4*)&At[kk][4 * tn];
            float4 bb = *(const float4*)&Bt[kk][4 * tm];
            acc[0][0] += a.x * bb.x; acc[0][1] += a.x * bb.y; acc[0][2] += a.x * bb.z; acc[0][3] += a.x * bb.w;
            acc[1][0] += a.y * bb.x; acc[1][1] += a.y * bb.y; acc[1][2] += a.y * bb.z; acc[1][3] += a.y * bb.w;
            acc[2][0] += a.z * bb.x; acc[2][1] += a.z * bb.y; acc[2][2] += a.z * bb.z; acc[2][3] += a.z * bb.w;
            acc[3][0] += a.w * bb.x; acc[3][1] += a.w * bb.y; acc[3][2] += a.w * bb.z; acc[3][3] += a.w * bb.w;
        }
    }
    #pragma unroll
    for (int i = 0; i < 4; i++)
        #pragma unroll
        for (int j = 0; j < 4; j++)
            outp[((size_t)b * 320 + o_base + 4 * tn + i) * ns + n_base + 4 * tm + j] = acc[i][j];
}

// ---------------------------------------------------------------------------
// K6M: full-res projection via bf16 MFMA, XCD-PINNED 1-D grid 640.
// obase==0 blocks additionally emit per-token |q|, |k| norms.
// ---------------------------------------------------------------------------
__global__ __launch_bounds__(256) void k6m(
    const unsigned short* __restrict__ WB, const unsigned short* __restrict__ x2T,
    const float* __restrict__ bq, const float* __restrict__ bk, const float* __restrict__ bv,
    const float* __restrict__ P2, const float* __restrict__ P4, const float* __restrict__ P8,
    unsigned short* __restrict__ qT, unsigned short* __restrict__ kT,
    unsigned short* __restrict__ vC, float* __restrict__ qn, float* __restrict__ kn)
{
    const int bid = blockIdx.x;
    const int b = (bid >> 1) & 3;
    const int rest = ((bid >> 3) << 1) | (bid & 1);   // 0..159
    const int nb = (rest & 31) * 128;
    const int obase = (rest >> 5) * 64;
    const int t = threadIdx.x;
    const int w_ = t >> 6, lane = t & 63;
    const int quad = lane >> 4, l16 = lane & 15;
    const int nbase = nb + 32 * w_;
    f32x4 acc[4][2];
    #pragma unroll
    for (int ot = 0; ot < 4; ot++)
        #pragma unroll
        for (int nt = 0; nt < 2; nt++) { acc[ot][nt][0] = 0.f; acc[ot][nt][1] = 0.f; acc[ot][nt][2] = 0.f; acc[ot][nt][3] = 0.f; }
    const unsigned short* xb = x2T + ((size_t)b * 4096 + nbase) * 256;
    for (int k0 = 0; k0 < 256; k0 += 32) {
        FRAG af[4], bf[2];
        #pragma unroll
        for (int ot = 0; ot < 4; ot++)
            af[ot].u = *(const uint4*)(WB + (size_t)(obase + 16 * ot + l16) * 256 + k0 + quad * 8);
        #pragma unroll
        for (int nt = 0; nt < 2; nt++)
            bf[nt].u = *(const uint4*)(xb + (size_t)(16 * nt + l16) * 256 + k0 + quad * 8);
        #pragma unroll
        for (int ot = 0; ot < 4; ot++)
            #pragma unroll
            for (int nt = 0; nt < 2; nt++)
                acc[ot][nt] = __builtin_amdgcn_mfma_f32_16x16x32_bf16(af[ot].s, bf[nt].s, acc[ot][nt], 0, 0, 0);
    }
    float qsq[2] = {0.f, 0.f}, ksq[2] = {0.f, 0.f};
    #pragma unroll
    for (int ot = 0; ot < 4; ot++) {
        #pragma unroll
        for (int nt = 0; nt < 2; nt++) {
            int n = nbase + 16 * nt + l16;
            int h = n >> 6, wx = n & 63;
            int i2 = ((h >> 1) << 5) + (wx >> 1);
            int i4 = ((h >> 2) << 4) + (wx >> 2);
            int i8 = ((h >> 3) << 3) + (wx >> 3);
            float vals[4];
            #pragma unroll
            for (int r = 0; r < 4; r++) {
                int o = obase + 16 * ot + 4 * quad + r;
                float bias = (o < 32) ? bq[o] : (o < 64) ? bk[o - 32] : bv[o - 64];
                size_t ro = (size_t)b * 320 + o;
                vals[r] = acc[ot][nt][r] + bias
                        + P2[ro * 1024 + i2] + P4[ro * 256 + i4] + P8[ro * 64 + i8];
            }
            float ss = vals[0] * vals[0] + vals[1] * vals[1]
                     + vals[2] * vals[2] + vals[3] * vals[3];
            if (ot < 2) qsq[nt] += ss; else ksq[nt] += ss;
            int o0 = obase + 16 * ot + 4 * quad;
            if (o0 < 64) {
                uint2 pk;
                pk.x = (unsigned)f2bf(vals[0]) | ((unsigned)f2bf(vals[1]) << 16);
                pk.y = (unsigned)f2bf(vals[2]) | ((unsigned)f2bf(vals[3]) << 16);
                if (o0 < 32)
                    *(uint2*)(qT + ((size_t)(b * 4096 + n)) * 32 + o0) = pk;
                else
                    *(uint2*)(kT + ((size_t)(b * 4096 + n)) * 32 + (o0 - 32)) = pk;
            } else {
                int chunk = n >> 6;
                int kk = n & 63;
                int khw_ = (kk >> 5) & 1, qd = (kk >> 3) & 3, ko = kk & 7;
                unsigned short* dst = vC + (((size_t)b * 64 + chunk) << 14);
                #pragma unroll
                for (int r = 0; r < 4; r++) {
                    int c = o0 - 64 + r;
                    dst[((((c >> 4) << 1) + khw_) << 9) + ((qd * 16 + (c & 15)) << 3) + ko] = f2bf(vals[r]);
                }
            }
        }
    }
    if (obase == 0) {
        #pragma unroll
        for (int nt = 0; nt < 2; nt++) {
            float q2 = qsq[nt], k2 = ksq[nt];
            q2 += __shfl_xor(q2, 16); q2 += __shfl_xor(q2, 32);
            k2 += __shfl_xor(k2, 16); k2 += __shfl_xor(k2, 32);
            if (quad == 0) {
                int n = nbase + 16 * nt + l16;
                qn[b * 4096 + n] = sqrtf(q2);
                kn[b * 4096 + n] = sqrtf(k2);
            }
        }
    }
}

// ---------------------------------------------------------------------------
// K7B v19 (kept from round 12 — fused mbound prologue measured ~neutral and
// deletes a launch): Cauchy-Schwarz shift bound computed in-block; softmax
// denominator self-accumulated; residual recomputed from x,g,spg.
// ---------------------------------------------------------------------------
__global__ __launch_bounds__(512) void k7b_attn(
    const unsigned short* __restrict__ qT, const unsigned short* __restrict__ kT,
    const unsigned short* __restrict__ vC, const float* __restrict__ qn,
    const float* __restrict__ kn, const float* __restrict__ x,
    const float* __restrict__ g, const float* __restrict__ spg,
    const float* __restrict__ gamma, float* __restrict__ outp)
{
    __shared__ __align__(16) unsigned short PL[2][64][64];  // 16 KB swizzled P
    __shared__ float SB[128][68];                           // 34.8 KB combine buffer
    __shared__ float gsh[256];
    __shared__ float ssh[64];
    __shared__ float lsh[2][64];
    __shared__ float ilsh[64];
    __shared__ float redk[8];
    const int bid = blockIdx.x;
    const int b = (bid >> 1) & 3;
    const int qbase = (((bid >> 3) << 1) | (bid & 1)) << 6;
    const int t = threadIdx.x;
    const int wid = t >> 6, lane = t & 63;
    const int cw = wid & 3, khw = wid >> 2;
    const int quad = lane >> 4, l16 = lane & 15;
    const int ntq = wid & 3;                // QK n-tile of this wave
    const int mt0 = 2 * khw, mt1 = 2 * khw + 1;
    const int nq = qbase + 16 * ntq + l16;  // column of this wave's P rows

    FRAG qf;
    qf.u = *(const uint4*)(qT + ((size_t)(b * 4096 + nq)) * 32 + quad * 8);

    // --- fused k_mbound: K = max_n |k_n| over this b, block-wide reduce ---
    {
        float kmx = 0.f;
        #pragma unroll
        for (int i = 0; i < 8; i++)
            kmx = fmaxf(kmx, kn[b * 4096 + t + 512 * i]);
        #pragma unroll
        for (int o = 1; o < 64; o <<= 1) kmx = fmaxf(kmx, __shfl_xor(kmx, o));
        if (lane == 0) redk[wid] = kmx;
    }
    __syncthreads();
    const float Kb = fmaxf(fmaxf(fmaxf(redk[0], redk[1]), fmaxf(redk[2], redk[3])),
                           fmaxf(fmaxf(redk[4], redk[5]), fmaxf(redk[6], redk[7])));
    const float mN = qn[b * 4096 + nq] * (1.02f * Kb);
    float l_run = 0.f;

    f32x4 acc[4][4];
    #pragma unroll
    for (int ct = 0; ct < 4; ct++)
        #pragma unroll
        for (int nt = 0; nt < 4; nt++) { acc[ct][nt][0] = 0.f; acc[ct][nt][1] = 0.f; acc[ct][nt][2] = 0.f; acc[ct][nt][3] = 0.f; }
    const unsigned short* kTb = kT + (size_t)b * 4096 * 32;
    const unsigned short* vfb = vC + ((size_t)b * 64 << 14)
                              + (((8 * cw) + khw) << 9) + lane * 8;

    const int po  = 4 * (quad & 1);
    const int pg0 = ((4 * khw + (quad >> 1)) ^ (l16 & 7));
    const int pg1 = ((4 * khw + 2 + (quad >> 1)) ^ (l16 & 7));
    const int pgr = ((4 * khw + quad) ^ (l16 & 7)) << 3;

    FRAG avA[4], avB[4], kc0, kc1;

#define AV_LOAD(AV, CH) do { \
    const unsigned short* vfj = vfb + ((size_t)(CH) << 14); \
    AV[0].u = *(const uint4*)(vfj); \
    AV[1].u = *(const uint4*)(vfj + 1024); \
    AV[2].u = *(const uint4*)(vfj + 2048); \
    AV[3].u = *(const uint4*)(vfj + 3072); \
} while (0)

#define KC_LOAD(CH) do { \
    const int mo_ = (CH) << 6; \
    kc0.u = *(const uint4*)(kTb + (size_t)(mo_ + 16 * mt0 + l16) * 32 + quad * 8); \
    kc1.u = *(const uint4*)(kTb + (size_t)(mo_ + 16 * mt1 + l16) * 32 + quad * 8); \
} while (0)

#define QK_EXP_STORE(DST) do { \
    f32x4 z; z[0] = 0.f; z[1] = 0.f; z[2] = 0.f; z[3] = 0.f; \
    f32x4 e0 = __builtin_amdgcn_mfma_f32_16x16x32_bf16(kc0.s, qf.s, z, 0, 0, 0); \
    f32x4 e1 = __builtin_amdgcn_mfma_f32_16x16x32_bf16(kc1.s, qf.s, z, 0, 0, 0); \
    union { float f; unsigned int u; } p0, p1, p2, p3; \
    uint2 pkA, pkB; \
    p0.f = __expf(e0[0] - mN); p1.f = __expf(e0[1] - mN); \
    p2.f = __expf(e0[2] - mN); p3.f = __expf(e0[3] - mN); \
    l_run += (p0.f + p1.f) + (p2.f + p3.f); \
    pkA.x = __builtin_amdgcn_perm(p1.u, p0.u, 0x07060302u); \
    pkA.y = __builtin_amdgcn_perm(p3.u, p2.u, 0x07060302u); \
    p0.f = __expf(e1[0] - mN); p1.f = __expf(e1[1] - mN); \
    p2.f = __expf(e1[2] - mN); p3.f = __expf(e1[3] - mN); \
    l_run += (p0.f + p1.f) + (p2.f + p3.f); \
    pkB.x = __builtin_amdgcn_perm(p1.u, p0.u, 0x07060302u); \
    pkB.y = __builtin_amdgcn_perm(p3.u, p2.u, 0x07060302u); \
    *(uint2*)&PL[DST][16 * ntq + l16][(pg0 << 3) + po] = pkA; \
    *(uint2*)&PL[DST][16 * ntq + l16][(pg1 << 3) + po] = pkB; \
} while (0)

#define PV_STEP(AV, CUR) do { \
    FRAG bp[4]; \
    _Pragma("unroll") \
    for (int nt = 0; nt < 4; nt++) \
        bp[nt].u = *(const uint4*)&PL[CUR][16 * nt + l16][pgr]; \
    __builtin_amdgcn_s_setprio(1); \
    _Pragma("unroll") \
    for (int ct = 0; ct < 4; ct++) { \
        _Pragma("unroll") \
        for (int nt = 0; nt < 4; nt++) \
            acc[ct][nt] = __builtin_amdgcn_mfma_f32_16x16x32_bf16(AV[ct].s, bp[nt].s, acc[ct][nt], 0, 0, 0); \
    } \
    __builtin_amdgcn_s_setprio(0); \
} while (0)

    // --- prologue: av(0); QK(0)->PL[0]; kc for chunk 1 ---
    AV_LOAD(avA, 0);
    KC_LOAD(0);
    QK_EXP_STORE(0);
    KC_LOAD(1);

    for (int jj = 0; jj < 32; jj++) {
        const int j = 2 * jj;
        __syncthreads();
        {
            AV_LOAD(avB, j + 1);
            QK_EXP_STORE(1);
            if (j < 62) KC_LOAD(j + 2);
        }
        PV_STEP(avA, 0);
        __syncthreads();
        if (j < 62) {
            AV_LOAD(avA, j + 2);
            QK_EXP_STORE(0);
            if (j < 61) KC_LOAD(j + 3);
        }
        PV_STEP(avB, 1);
    }
#undef AV_LOAD
#undef KC_LOAD
#undef QK_EXP_STORE
#undef PV_STEP

    // l: reduce across quads -> per-(ntq,l16) half-sum.
    l_run += __shfl_xor(l_run, 16);
    l_run += __shfl_xor(l_run, 32);
    if (quad == 0) lsh[khw][16 * ntq + l16] = l_run;

    // residual gate factors for the epilogue
    if (t < 256) gsh[t] = g[(b << 8) + t];
    else if (t < 320) ssh[t - 256] = spg[(size_t)b * 4096 + qbase + (t - 256)];

    // --- epilogue: combine khw halves via SB, 2 c-stripe rounds ---
    const float gm = gamma[0];
    for (int s = 0; s < 2; s++) {
        __syncthreads();
        if (s == 0 && t < 64) ilsh[t] = 1.f / (lsh[0][t] + lsh[1][t]);
        if (khw == 0 && (cw >> 1) == s) {
            #pragma unroll
            for (int ct = 0; ct < 4; ct++)
                #pragma unroll
                for (int nt = 0; nt < 4; nt++)
                    #pragma unroll
                    for (int r = 0; r < 4; r++)
                        SB[64 * (cw & 1) + 16 * ct + 4 * quad + r][16 * nt + l16] = acc[ct][nt][r];
        }
        __syncthreads();
        if (khw == 1 && (cw >> 1) == s) {
            #pragma unroll
            for (int ct = 0; ct < 4; ct++)
                #pragma unroll
                for (int nt = 0; nt < 4; nt++)
                    #pragma unroll
                    for (int r = 0; r < 4; r++)
                        SB[64 * (cw & 1) + 16 * ct + 4 * quad + r][16 * nt + l16] += acc[ct][nt][r];
        }
        __syncthreads();
        // cooperative store: 128c x 64n
        #pragma unroll
        for (int pass = 0; pass < 4; pass++) {
            int cl = (t >> 4) + 32 * pass;
            int n4 = (t & 15) * 4;
            float4 vv = *(float4*)&SB[cl][n4];
            float4 il4 = *(float4*)&ilsh[n4];
            size_t idx = ((size_t)(b * 256 + 128 * s + cl)) * 4096 + qbase + n4;
            float4 xv = *(const float4*)(x + idx);
            float gc = gsh[128 * s + cl];
            float4 ss4 = *(float4*)&ssh[n4];
            float4 ov;
            ov.x = gm * vv.x * il4.x + xv.x * (gc * ss4.x);
            ov.y = gm * vv.y * il4.y + xv.y * (gc * ss4.y);
            ov.z = gm * vv.z * il4.z + xv.z * (gc * ss4.z);
            ov.w = gm * vv.w * il4.w + xv.w * (gc * ss4.w);
            *(float4*)(outp + idx) = ov;
        }
    }
}

// ---------------------------------------------------------------------------
extern "C" void kernel_launch(void* const* d_in, const int* in_sizes, int n_in,
                              void* d_out, int out_size, void* d_ws, size_t ws_size,
                              hipStream_t stream) {
    (void)in_sizes; (void)n_in; (void)out_size; (void)ws_size;
    const float* x    = (const float*)d_in[0];
    const float* W1   = (const float*)d_in[1];
    const float* b1   = (const float*)d_in[2];
    const float* W2   = (const float*)d_in[3];
    const float* b2   = (const float*)d_in[4];
    const float* Wq   = (const float*)d_in[5];
    const float* bq   = (const float*)d_in[6];
    const float* Wk   = (const float*)d_in[7];
    const float* bk   = (const float*)d_in[8];
    const float* Wv   = (const float*)d_in[9];
    const float* bv   = (const float*)d_in[10];
    const float* gam  = (const float*)d_in[11];
    const float* Wsp  = (const float*)d_in[12];
    const float* bn_g = (const float*)d_in[13];
    const float* bn_b = (const float*)d_in[14];
    const float* bn_m = (const float*)d_in[15];
    const float* bn_v = (const float*)d_in[16];

    float* ws = (float*)d_ws;
    float* bm2   = ws; ws += (size_t)4 * 256 * 1024;
    float* bm4   = ws; ws += (size_t)4 * 256 * 256;
    float* bm8   = ws; ws += (size_t)4 * 256 * 64;
    float* featA = ws; ws += 1024;
    float* fm1   = ws; ws += 1024;
    float* fm2   = ws; ws += 1024;
    float* fm4   = ws; ws += 1024;
    float* fm8   = ws; ws += 1024;
    float* g     = ws; ws += 1024;
    float* comp  = ws; ws += (size_t)4 * 2 * 4096;
    float* spg   = ws; ws += (size_t)4 * 4096;
    float* bm2b  = ws; ws += (size_t)4 * 256 * 1024;
    float* bm4b  = ws; ws += (size_t)4 * 256 * 256;
    float* bm8b  = ws; ws += (size_t)4 * 256 * 64;
    float* P2    = ws; ws += (size_t)4 * 320 * 1024;
    float* P4    = ws; ws += (size_t)4 * 320 * 256;
    float* P8    = ws; ws += (size_t)4 * 320 * 64;
    float* qn    = ws; ws += (size_t)4 * 4096;
    float* kn    = ws; ws += (size_t)4 * 4096;
    unsigned short* qT  = (unsigned short*)ws; ws += (size_t)4 * 4096 * 32 / 2;
    unsigned short* kT  = (unsigned short*)ws; ws += (size_t)4 * 4096 * 32 / 2;
    unsigned short* vCp = (unsigned short*)ws; ws += (size_t)4 * 64 * 16384 / 2;
    unsigned short* x2T = (unsigned short*)ws; ws += (size_t)4 * 4096 * 256 / 2;
    unsigned short* WB  = (unsigned short*)ws; ws += (size_t)320 * 256 / 2;

    // Stage 1: channel gate (pyramid + fused weight-cast)
    k_pyramid<<<1104, 256, 0, stream>>>(x, bm2, bm4, bm8,
                                        featA, fm1, fm2, fm4, fm8,
                                        Wq, Wk, Wv, WB);
    // Stage 2: spatial gate (k3 with fused channel-gate MLP; 8 waves)
    k3_comp<<<256, 512, 0, stream>>>(x, bm2, bm4, bm8,
                                     featA, fm1, fm2, fm4, fm8,
                                     W1, b1, W2, b2, g, comp);
    k4_spgate<<<64, 256, 0, stream>>>(comp, Wsp, bn_g, bn_b, bn_m, bn_v, spg);
    // Fused gate+transpose+pool2, then bm4b/bm8b (restored streamer)
    k_x2tp<<<dim3(32, 4, 4), 256, 0, stream>>>(x, g, spg, x2T, bm2b);
    k_pool48<<<1024, 256, 0, stream>>>(bm2b, bm4b, bm8b);
    // Stage 3: q/k/v projections (+ per-token q/k norms)
    k6_gemm<<<dim3(21, 5, 4), 256, 0, stream>>>(Wq, Wk, Wv, bm2b, bm4b, bm8b, P2, P4, P8);
    k6m<<<640, 256, 0, stream>>>(WB, x2T, bq, bk, bv, P2, P4, P8, qT, kT, vCp, qn, kn);
    // Attention: single pass; shift bound + denominator computed in-kernel
    k7b_attn<<<256, 512, 0, stream>>>(qT, kT, vCp, qn, kn, x, g, spg, gam, (float*)d_out);
}

// Round 14
// 224.105 us; speedup vs baseline: 1.1062x; 1.0521x over previous
//
#include <hip/hip_runtime.h>
#include <math.h>

// Shapes (fixed): B=4, C=256, H=W=64, N=4096, 4C=1024, c8=32, r=16.

typedef float f32x4 __attribute__((ext_vector_type(4)));
typedef short s16x8 __attribute__((ext_vector_type(8)));
union FRAG { uint4 u; s16x8 s; };

__device__ __forceinline__ unsigned short f2bf(float f) {
    union { float f; unsigned int u; } v; v.f = f;
    unsigned int r = v.u + 0x7FFFu + ((v.u >> 16) & 1u);
    return (unsigned short)(r >> 16);
}

// ---------------------------------------------------------------------------
// K1: per-(b,c) plane -> block-mean pyramid + feats.
// Carries 80 extra blocks (bc >= 1024) doing the WB bf16 weight-cast.
// ---------------------------------------------------------------------------
__global__ __launch_bounds__(256) void k_pyramid(
    const float* __restrict__ xin,
    float* __restrict__ bm2, float* __restrict__ bm4, float* __restrict__ bm8,
    float* __restrict__ featA, float* __restrict__ fm1, float* __restrict__ fm2,
    float* __restrict__ fm4, float* __restrict__ fm8,
    const float* __restrict__ Wq, const float* __restrict__ Wk,
    const float* __restrict__ Wv, unsigned short* __restrict__ WB)
{
    __shared__ float sx[4096];
    __shared__ float s2[1024];
    __shared__ float s4[256];
    __shared__ float wred[4][8];
    const int bc = blockIdx.x;
    const int t = threadIdx.x;
    if (bc >= 1024) {
        const int e0 = (bc - 1024) * 1024 + t * 4;
        const int o = e0 >> 8, col = e0 & 255;
        const float* row = (o < 32) ? (Wq + (size_t)o * 1024)
                          : (o < 64) ? (Wk + (size_t)(o - 32) * 1024)
                                     : (Wv + (size_t)(o - 64) * 1024);
        float4 v = *(const float4*)(row + 768 + col);
        uint2 pk;
        pk.x = (unsigned)f2bf(v.x) | ((unsigned)f2bf(v.y) << 16);
        pk.y = (unsigned)f2bf(v.z) | ((unsigned)f2bf(v.w) << 16);
        *(uint2*)(WB + e0) = pk;
        return;
    }
    const float* xp = xin + (size_t)bc * 4096;
    float sum = 0.f, mx = -1e30f;
    for (int r = 0; r < 4; r++) {
        int i4 = t + 256 * r;
        float4 v = ((const float4*)xp)[i4];
        sum += v.x + v.y + v.z + v.w;
        mx = fmaxf(mx, fmaxf(fmaxf(v.x, v.y), fmaxf(v.z, v.w)));
        ((float4*)sx)[i4] = v;
    }
    __syncthreads();
    float mx2 = -1e30f;
    for (int r = 0; r < 4; r++) {
        int i = t + 256 * r;
        int r2 = i >> 5, c2 = i & 31;
        int p0 = 128 * r2 + 2 * c2;
        float v = 0.25f * (sx[p0] + sx[p0 + 1] + sx[p0 + 64] + sx[p0 + 65]);
        s2[i] = v;
        bm2[(size_t)bc * 1024 + i] = v;
        mx2 = fmaxf(mx2, v);
    }
    __syncthreads();
    float mx4;
    {
        int r4 = t >> 4, c4 = t & 15;
        int p0 = 64 * r4 + 2 * c4;
        float v = 0.25f * (s2[p0] + s2[p0 + 1] + s2[p0 + 32] + s2[p0 + 33]);
        s4[t] = v;
        bm4[(size_t)bc * 256 + t] = v;
        mx4 = v;
    }
    __syncthreads();
    float mx8 = -1e30f;
    if (t < 64) {
        int r8 = t >> 3, c8 = t & 7;
        int p0 = 32 * r8 + 2 * c8;
        float v = 0.25f * (s4[p0] + s4[p0 + 1] + s4[p0 + 16] + s4[p0 + 17]);
        bm8[(size_t)bc * 64 + t] = v;
        mx8 = v;
    }
    {
        float vs = sum, v1 = mx, v2 = mx2, v4 = mx4, v8 = mx8;
        #pragma unroll
        for (int o = 1; o < 64; o <<= 1) {
            vs += __shfl_xor(vs, o);
            v1 = fmaxf(v1, __shfl_xor(v1, o));
            v2 = fmaxf(v2, __shfl_xor(v2, o));
            v4 = fmaxf(v4, __shfl_xor(v4, o));
            v8 = fmaxf(v8, __shfl_xor(v8, o));
        }
        if ((t & 63) == 0) {
            int wd = t >> 6;
            wred[wd][0] = vs; wred[wd][1] = v1; wred[wd][2] = v2;
            wred[wd][3] = v4; wred[wd][4] = v8;
        }
        __syncthreads();
        if (t == 0) featA[bc] = (wred[0][0] + wred[1][0] + wred[2][0] + wred[3][0]) * (1.f / 4096.f);
        else if (t == 1) fm1[bc] = fmaxf(fmaxf(wred[0][1], wred[1][1]), fmaxf(wred[2][1], wred[3][1]));
        else if (t == 2) fm2[bc] = fmaxf(fmaxf(wred[0][2], wred[1][2]), fmaxf(wred[2][2], wred[3][2]));
        else if (t == 3) fm4[bc] = fmaxf(fmaxf(wred[0][3], wred[1][3]), fmaxf(wred[2][3], wred[3][3]));
        else if (t == 4) fm8[bc] = fmaxf(fmaxf(wred[0][4], wred[1][4]), fmaxf(wred[2][4], wred[3][4]));
    }
}

// ---------------------------------------------------------------------------
// K3: spatial-gate input with fused channel-gate MLP (8 waves).
// ---------------------------------------------------------------------------
__global__ __launch_bounds__(512) void k3_comp(
    const float* __restrict__ x, const float* __restrict__ bm2,
    const float* __restrict__ bm4, const float* __restrict__ bm8,
    const float* __restrict__ featA, const float* __restrict__ fm1,
    const float* __restrict__ fm2, const float* __restrict__ fm4,
    const float* __restrict__ fm8,
    const float* __restrict__ W1, const float* __restrict__ b1,
    const float* __restrict__ W2, const float* __restrict__ b2,
    float* __restrict__ g, float* __restrict__ comp)
{
    __shared__ float sf[5][256];
    __shared__ float sh[5][16];
    __shared__ float hs[16];
    __shared__ float sg[256];
    __shared__ float rmx[8][64];
    __shared__ float rsm[8][64];
    const int b = blockIdx.x >> 6;
    const int t = threadIdx.x;
    if (t < 256) {
        sf[0][t] = featA[(b << 8) + t];
        sf[1][t] = fm1[(b << 8) + t];
        sf[2][t] = fm2[(b << 8) + t];
        sf[3][t] = fm4[(b << 8) + t];
        sf[4][t] = fm8[(b << 8) + t];
    }
    __syncthreads();
    if (t < 80) {
        int f = t / 16, j = t % 16;
        float a = b1[j];
        for (int c = 0; c < 256; c++) a += sf[f][c] * W1[c * 16 + j];
        sh[f][j] = fmaxf(a, 0.f);
    }
    __syncthreads();
    if (t < 16) hs[t] = 4.f * sh[0][t] + sh[1][t] + sh[2][t] + sh[3][t] + sh[4][t];
    __syncthreads();
    if (t < 256) {
        float a = 8.f * b2[t];
        for (int j = 0; j < 16; j++) a += hs[j] * W2[j * 256 + t];
        sg[t] = 1.f / (1.f + __expf(-a));
    }
    __syncthreads();
    if ((blockIdx.x & 63) == 0 && t < 256) g[(b << 8) + t] = sg[t];
    const int pix = ((blockIdx.x & 63) << 6) + (t & 63);
    const int wid = t >> 6;
    const int c0 = wid << 5;
    const int h = pix >> 6, w = pix & 63;
    const int i2 = ((h >> 1) << 5) + (w >> 1);
    const int i4 = ((h >> 2) << 4) + (w >> 2);
    const int i8 = ((h >> 3) << 3) + (w >> 3);
    const float* xb = x + ((size_t)b << 8) * 4096;
    const float* p2 = bm2 + ((size_t)b << 8) * 1024;
    const float* p4 = bm4 + ((size_t)b << 8) * 256;
    const float* p8 = bm8 + ((size_t)b << 8) * 64;
    float mx = -1e30f, sm = 0.f;
    for (int c = c0; c < c0 + 32; c++) {
        float gc = sg[c];
        float xv = xb[(size_t)c * 4096 + pix] * gc;
        float v2 = p2[c * 1024 + i2] * gc;
        float v4 = p4[c * 256 + i4] * gc;
        float v8 = p8[c * 64 + i8] * gc;
        mx = fmaxf(fmaxf(mx, xv), fmaxf(fmaxf(v2, v4), v8));
        sm += xv + v2 + v4 + v8;
    }
    rmx[wid][t & 63] = mx;
    rsm[wid][t & 63] = sm;
    __syncthreads();
    if (wid == 0) {
        int l = t;
        float m = rmx[0][l], s = rsm[0][l];
        #pragma unroll
        for (int wsrc = 1; wsrc < 8; wsrc++) {
            m = fmaxf(m, rmx[wsrc][l]);
            s += rsm[wsrc][l];
        }
        comp[((size_t)b * 2) * 4096 + pix] = m;
        comp[((size_t)b * 2 + 1) * 4096 + pix] = s * (1.f / 1024.f);
    }
}

// ---------------------------------------------------------------------------
// K_X2TP v2: fused spatial-gate-conv + gate + transpose + pool2.
// Former k4_spgate absorbed: each block stages an 8-row comp halo (4 KB)
// and computes its 128 spg values with the IDENTICAL fp32 conv/BN/sigmoid
// expression (bit-identical); writes spg for k7b (4x duplicate across cb
// blocks, same value). Deletes the k4 launch and one dependency stage.
// ---------------------------------------------------------------------------
__global__ __launch_bounds__(256) void k_x2tp(
    const float* __restrict__ x, const float* __restrict__ g,
    const float* __restrict__ comp, const float* __restrict__ Wsp,
    const float* __restrict__ bn_g, const float* __restrict__ bn_b,
    const float* __restrict__ bn_m, const float* __restrict__ bn_v,
    unsigned short* __restrict__ x2T, float* __restrict__ bm2b,
    float* __restrict__ spg)
{
    __shared__ float sx[128][68];
    __shared__ float gsh[64];
    __shared__ float ssh[128];
    __shared__ float csh[2][8][64];
    __shared__ float wsh[98];
    const int b  = blockIdx.z;
    const int cb = blockIdx.y * 64;
    const int nb = blockIdx.x * 128;
    const int t  = threadIdx.x;
    const int h0 = nb >> 6;                  // first of the block's 2 rows
    if (t < 98) wsh[t] = Wsp[t];
    if (t < 64) gsh[t] = g[(b << 8) + cb + t];
    #pragma unroll
    for (int i = 0; i < 4; i++) {
        int idx = t + 256 * i;               // 0..1023
        int ci = idx >> 9, rl = (idx >> 6) & 7, ww = idx & 63;
        int hh = h0 - 3 + rl;
        csh[ci][rl][ww] = (hh >= 0 && hh < 64)
                        ? comp[((size_t)b * 2 + ci) * 4096 + hh * 64 + ww] : 0.f;
    }
    __syncthreads();
    if (t < 128) {
        int p = nb + t;
        int h = p >> 6, wx = p & 63;
        int dh = h - h0;                     // 0 or 1
        float acc = 0.f;
        for (int ci = 0; ci < 2; ci++)
            for (int kh = 0; kh < 7; kh++) {
                int hh = h + kh - 3;
                if (hh < 0 || hh >= 64) continue;
                int rl = dh + kh;            // == hh - h0 + 3
                for (int kw = 0; kw < 7; kw++) {
                    int wwp = wx + kw - 3;
                    if (wwp < 0 || wwp >= 64) continue;
                    acc += csh[ci][rl][wwp] * wsh[ci * 49 + kh * 7 + kw];
                }
            }
        float sc = rsqrtf(bn_v[0] + 1e-5f) * bn_g[0];
        float sp = (acc - bn_m[0]) * sc + bn_b[0];
        float sv = 1.f / (1.f + __expf(-sp));
        ssh[t] = sv;
        spg[(size_t)b * 4096 + p] = sv;      // duplicate-writes same value
    }
    __syncthreads();
    const int nl = t & 127;
    const int ch = t >> 7;
    const float sp = ssh[nl];
    #pragma unroll
    for (int r = 0; r < 32; r++) {
        int cl = ch + 2 * r;
        float v = x[((size_t)(b * 256 + cb + cl)) * 4096 + nb + nl];
        sx[nl][cl] = v * (gsh[cl] * sp);
    }
    __syncthreads();
    #pragma unroll
    for (int pass = 0; pass < 8; pass++) {
        int nl2 = (t >> 4) + 16 * pass;
        int c4 = (t & 15) * 4;
        uint2 pk;
        pk.x = (unsigned)f2bf(sx[nl2][c4])     | ((unsigned)f2bf(sx[nl2][c4 + 1]) << 16);
        pk.y = (unsigned)f2bf(sx[nl2][c4 + 2]) | ((unsigned)f2bf(sx[nl2][c4 + 3]) << 16);
        *(uint2*)(x2T + ((size_t)(b * 4096 + nb + nl2)) * 256 + cb + c4) = pk;
    }
    #pragma unroll
    for (int i = 0; i < 8; i++) {
        int o = t + 256 * i;
        int c = o >> 5, w2 = o & 31;
        float v = 0.25f * (sx[2 * w2][c] + sx[2 * w2 + 1][c]
                         + sx[64 + 2 * w2][c] + sx[64 + 2 * w2 + 1][c]);
        bm2b[((size_t)(b * 256 + cb + c)) * 1024 + (nb >> 7) * 32 + w2] = v;
    }
}

// ---------------------------------------------------------------------------
// K_POOL48: bm2b -> bm4b, bm8b.
// ---------------------------------------------------------------------------
__global__ __launch_bounds__(256) void k_pool48(
    const float* __restrict__ bm2b, float* __restrict__ bm4b, float* __restrict__ bm8b)
{
    __shared__ float s2[1024];
    __shared__ float s4[256];
    const int bc = blockIdx.x;
    const int t = threadIdx.x;
    ((float4*)s2)[t] = ((const float4*)(bm2b + (size_t)bc * 1024))[t];
    __syncthreads();
    {
        int r4 = t >> 4, c4 = t & 15;
        int p0 = 64 * r4 + 2 * c4;
        float v = 0.25f * (s2[p0] + s2[p0 + 1] + s2[p0 + 32] + s2[p0 + 33]);
        s4[t] = v;
        bm4b[(size_t)bc * 256 + t] = v;
    }
    __syncthreads();
    if (t < 64) {
        int r8 = t >> 3, c8 = t & 7;
        int p0 = 32 * r8 + 2 * c8;
        bm8b[(size_t)bc * 64 + t] = 0.25f * (s4[p0] + s4[p0 + 1] + s4[p0 + 16] + s4[p0 + 17]);
    }
}

// ---------------------------------------------------------------------------
// K6 v2: fp32 projection GEMM for low-res P2/P4/P8.
// P2 blocks (bx<8) use a 64o x 128n tile with 4x8 register tiles: 32 FMA
// per 12 LDS floats (was 16 per 8) — same k-accumulation order, bit-identical.
// P4/P8 keep the proven 4x4 path. Grid (13, 5, 4).
// ---------------------------------------------------------------------------
__global__ __launch_bounds__(256) void k6_gemm(
    const float* __restrict__ Wq, const float* __restrict__ Wk, const float* __restrict__ Wv,
    const float* __restrict__ bm2b, const float* __restrict__ bm4b, const float* __restrict__ bm8b,
    float* __restrict__ P2, float* __restrict__ P4, float* __restrict__ P8)
{
    __shared__ float At[32][68];
    __shared__ float Bt[32][128];
    const int bx = blockIdx.x;
    const int b = blockIdx.z;
    const int o_base = blockIdx.y * 64;
    const int t = threadIdx.x;
    const int lk = t & 31, lo8 = t >> 5;

    if (bx < 8) {
        // ---- wide path: P2, 64o x 128n, 4x8 per-thread tile ----
        const int n_base = bx * 128;
        const int tn = t >> 4, tm = t & 15;          // o-group, n-group
        const int lnw = t & 127, lkh = t >> 7;       // B loader
        float acc[4][8];
        #pragma unroll
        for (int i = 0; i < 4; i++)
            #pragma unroll
            for (int j = 0; j < 8; j++) acc[i][j] = 0.f;
        for (int k0 = 0; k0 < 256; k0 += 32) {
            __syncthreads();
            #pragma unroll
            for (int r = 0; r < 8; r++) {
                int o = o_base + lo8 + 8 * r;
                const float* wrow = (o < 32) ? (Wq + (size_t)o * 1024)
                                  : (o < 64) ? (Wk + (size_t)(o - 32) * 1024)
                                             : (Wv + (size_t)(o - 64) * 1024);
                At[lk][lo8 + 8 * r] = wrow[k0 + lk];
            }
            #pragma unroll
            for (int r = 0; r < 16; r++)
                Bt[lkh + 2 * r][lnw] = bm2b[((size_t)b * 256 + k0 + lkh + 2 * r) * 1024 + n_base + lnw];
            __syncthreads();
            #pragma unroll
            for (int kk = 0; kk < 32; kk++) {
                float4 a  = *(const float4*)&At[kk][4 * tn];
                float4 b0 = *(const float4*)&Bt[kk][8 * tm];
                float4 b1 = *(const float4*)&Bt[kk][8 * tm + 4];
                #pragma unroll
                for (int i = 0; i < 4; i++) {
                    float ai = (i == 0) ? a.x : (i == 1) ? a.y : (i == 2) ? a.z : a.w;
                    acc[i][0] += ai * b0.x; acc[i][1] += ai * b0.y;
                    acc[i][2] += ai * b0.z; acc[i][3] += ai * b0.w;
                    acc[i][4] += ai * b1.x; acc[i][5] += ai * b1.y;
                    acc[i][6] += ai * b1.z; acc[i][7] += ai * b1.w;
                }
            }
        }
        #pragma unroll
        for (int i = 0; i < 4; i++)
            #pragma unroll
            for (int j = 0; j < 8; j++)
                P2[((size_t)b * 320 + o_base + 4 * tn + i) * 1024 + n_base + 8 * tm + j] = acc[i][j];
    } else {
        // ---- narrow path: P4 (bx 8..11) / P8 (bx 12), 64o x 64n, 4x4 ----
        int col_off, ns, n_base;
        const float* src;
        float* outp;
        if (bx < 12) { col_off = 256; src = bm4b; ns = 256; outp = P4; n_base = (bx - 8) * 64; }
        else         { col_off = 512; src = bm8b; ns = 64;  outp = P8; n_base = 0; }
        const int tn = t >> 4, tm = t & 15;
        const int ln = t & 63, lk4 = t >> 6;
        float acc[4][4];
        #pragma unroll
        for (int i = 0; i < 4; i++)
            #pragma unroll
            for (int j = 0; j < 4; j++) acc[i][j] = 0.f;
        for (int k0 = 0; k0 < 256; k0 += 32) {
            __syncthreads();
            #pragma unroll
            for (int r = 0; r < 8; r++) {
                int o = o_base + lo8 + 8 * r;
                const float* wrow = (o < 32) ? (Wq + (size_t)o * 1024)
                                  : (o < 64) ? (Wk + (size_t)(o - 32) * 1024)
                                             : (Wv + (size_t)(o - 64) * 1024);
                At[lk][lo8 + 8 * r] = wrow[col_off + k0 + lk];
            }
            #pragma unroll
            for (int r = 0; r < 8; r++)
                Bt[lk4 + 4 * r][ln] = src[((size_t)b * 256 + k0 + lk4 + 4 * r) * ns + n_base + ln];
            __syncthreads();
            #pragma unroll
            for (int kk = 0; kk < 32; kk++) {
                float4 a = *(const float4*)&At[kk][4 * tn];
                float4 bb = *(const float4*)&Bt[kk][4 * tm];
                acc[0][0] += a.x * bb.x; acc[0][1] += a.x * bb.y; acc[0][2] += a.x * bb.z; acc[0][3] += a.x * bb.w;
                acc[1][0] += a.y * bb.x; acc[1][1] += a.y * bb.y; acc[1][2] += a.y * bb.z; acc[1][3] += a.y * bb.w;
                acc[2][0] += a.z * bb.x; acc[2][1] += a.z * bb.y; acc[2][2] += a.z * bb.z; acc[2][3] += a.z * bb.w;
                acc[3][0] += a.w * bb.x; acc[3][1] += a.w * bb.y; acc[3][2] += a.w * bb.z; acc[3][3] += a.w * bb.w;
            }
        }
        #pragma unroll
        for (int i = 0; i < 4; i++)
            #pragma unroll
            for (int j = 0; j < 4; j++)
                outp[((size_t)b * 320 + o_base + 4 * tn + i) * ns + n_base + 4 * tm + j] = acc[i][j];
    }
}

// ---------------------------------------------------------------------------
// K6M: full-res projection via bf16 MFMA, XCD-PINNED 1-D grid 640.
// obase==0 blocks additionally emit per-token |q|, |k| norms.
// ---------------------------------------------------------------------------
__global__ __launch_bounds__(256) void k6m(
    const unsigned short* __restrict__ WB, const unsigned short* __restrict__ x2T,
    const float* __restrict__ bq, const float* __restrict__ bk, const float* __restrict__ bv,
    const float* __restrict__ P2, const float* __restrict__ P4, const float* __restrict__ P8,
    unsigned short* __restrict__ qT, unsigned short* __restrict__ kT,
    unsigned short* __restrict__ vC, float* __restrict__ qn, float* __restrict__ kn)
{
    const int bid = blockIdx.x;
    const int b = (bid >> 1) & 3;
    const int rest = ((bid >> 3) << 1) | (bid & 1);   // 0..159
    const int nb = (rest & 31) * 128;
    const int obase = (rest >> 5) * 64;
    const int t = threadIdx.x;
    const int w_ = t >> 6, lane = t & 63;
    const int quad = lane >> 4, l16 = lane & 15;
    const int nbase = nb + 32 * w_;
    f32x4 acc[4][2];
    #pragma unroll
    for (int ot = 0; ot < 4; ot++)
        #pragma unroll
        for (int nt = 0; nt < 2; nt++) { acc[ot][nt][0] = 0.f; acc[ot][nt][1] = 0.f; acc[ot][nt][2] = 0.f; acc[ot][nt][3] = 0.f; }
    const unsigned short* xb = x2T + ((size_t)b * 4096 + nbase) * 256;
    for (int k0 = 0; k0 < 256; k0 += 32) {
        FRAG af[4], bf[2];
        #pragma unroll
        for (int ot = 0; ot < 4; ot++)
            af[ot].u = *(const uint4*)(WB + (size_t)(obase + 16 * ot + l16) * 256 + k0 + quad * 8);
        #pragma unroll
        for (int nt = 0; nt < 2; nt++)
            bf[nt].u = *(const uint4*)(xb + (size_t)(16 * nt + l16) * 256 + k0 + quad * 8);
        #pragma unroll
        for (int ot = 0; ot < 4; ot++)
            #pragma unroll
            for (int nt = 0; nt < 2; nt++)
                acc[ot][nt] = __builtin_amdgcn_mfma_f32_16x16x32_bf16(af[ot].s, bf[nt].s, acc[ot][nt], 0, 0, 0);
    }
    float qsq[2] = {0.f, 0.f}, ksq[2] = {0.f, 0.f};
    #pragma unroll
    for (int ot = 0; ot < 4; ot++) {
        #pragma unroll
        for (int nt = 0; nt < 2; nt++) {
            int n = nbase + 16 * nt + l16;
            int h = n >> 6, wx = n & 63;
            int i2 = ((h >> 1) << 5) + (wx >> 1);
            int i4 = ((h >> 2) << 4) + (wx >> 2);
            int i8 = ((h >> 3) << 3) + (wx >> 3);
            float vals[4];
            #pragma unroll
            for (int r = 0; r < 4; r++) {
                int o = obase + 16 * ot + 4 * quad + r;
                float bias = (o < 32) ? bq[o] : (o < 64) ? bk[o - 32] : bv[o - 64];
                size_t ro = (size_t)b * 320 + o;
                vals[r] = acc[ot][nt][r] + bias
                        + P2[ro * 1024 + i2] + P4[ro * 256 + i4] + P8[ro * 64 + i8];
            }
            float ss = vals[0] * vals[0] + vals[1] * vals[1]
                     + vals[2] * vals[2] + vals[3] * vals[3];
            if (ot < 2) qsq[nt] += ss; else ksq[nt] += ss;
            int o0 = obase + 16 * ot + 4 * quad;
            if (o0 < 64) {
                uint2 pk;
                pk.x = (unsigned)f2bf(vals[0]) | ((unsigned)f2bf(vals[1]) << 16);
                pk.y = (unsigned)f2bf(vals[2]) | ((unsigned)f2bf(vals[3]) << 16);
                if (o0 < 32)
                    *(uint2*)(qT + ((size_t)(b * 4096 + n)) * 32 + o0) = pk;
                else
                    *(uint2*)(kT + ((size_t)(b * 4096 + n)) * 32 + (o0 - 32)) = pk;
            } else {
                int chunk = n >> 6;
                int kk = n & 63;
                int khw_ = (kk >> 5) & 1, qd = (kk >> 3) & 3, ko = kk & 7;
                unsigned short* dst = vC + (((size_t)b * 64 + chunk) << 14);
                #pragma unroll
                for (int r = 0; r < 4; r++) {
                    int c = o0 - 64 + r;
                    dst[((((c >> 4) << 1) + khw_) << 9) + ((qd * 16 + (c & 15)) << 3) + ko] = f2bf(vals[r]);
                }
            }
        }
    }
    if (obase == 0) {
        #pragma unroll
        for (int nt = 0; nt < 2; nt++) {
            float q2 = qsq[nt], k2 = ksq[nt];
            q2 += __shfl_xor(q2, 16); q2 += __shfl_xor(q2, 32);
            k2 += __shfl_xor(k2, 16); k2 += __shfl_xor(k2, 32);
            if (quad == 0) {
                int n = nbase + 16 * nt + l16;
                qn[b * 4096 + n] = sqrtf(q2);
                kn[b * 4096 + n] = sqrtf(k2);
            }
        }
    }
}

// ---------------------------------------------------------------------------
// K7B v19: Cauchy-Schwarz shift bound computed in-block; softmax denominator
// self-accumulated; residual recomputed from x,g,spg.
// ---------------------------------------------------------------------------
__global__ __launch_bounds__(512) void k7b_attn(
    const unsigned short* __restrict__ qT, const unsigned short* __restrict__ kT,
    const unsigned short* __restrict__ vC, const float* __restrict__ qn,
    const float* __restrict__ kn, const float* __restrict__ x,
    const float* __restrict__ g, const float* __restrict__ spg,
    const float* __restrict__ gamma, float* __restrict__ outp)
{
    __shared__ __align__(16) unsigned short PL[2][64][64];  // 16 KB swizzled P
    __shared__ float SB[128][68];                           // 34.8 KB combine buffer
    __shared__ float gsh[256];
    __shared__ float ssh[64];
    __shared__ float lsh[2][64];
    __shared__ float ilsh[64];
    __shared__ float redk[8];
    const int bid = blockIdx.x;
    const int b = (bid >> 1) & 3;
    const int qbase = (((bid >> 3) << 1) | (bid & 1)) << 6;
    const int t = threadIdx.x;
    const int wid = t >> 6, lane = t & 63;
    const int cw = wid & 3, khw = wid >> 2;
    const int quad = lane >> 4, l16 = lane & 15;
    const int ntq = wid & 3;                // QK n-tile of this wave
    const int mt0 = 2 * khw, mt1 = 2 * khw + 1;
    const int nq = qbase + 16 * ntq + l16;  // column of this wave's P rows

    FRAG qf;
    qf.u = *(const uint4*)(qT + ((size_t)(b * 4096 + nq)) * 32 + quad * 8);

    // --- fused k_mbound: K = max_n |k_n| over this b, block-wide reduce ---
    {
        float kmx = 0.f;
        #pragma unroll
        for (int i = 0; i < 8; i++)
            kmx = fmaxf(kmx, kn[b * 4096 + t + 512 * i]);
        #pragma unroll
        for (int o = 1; o < 64; o <<= 1) kmx = fmaxf(kmx, __shfl_xor(kmx, o));
        if (lane == 0) redk[wid] = kmx;
    }
    __syncthreads();
    const float Kb = fmaxf(fmaxf(fmaxf(redk[0], redk[1]), fmaxf(redk[2], redk[3])),
                           fmaxf(fmaxf(redk[4], redk[5]), fmaxf(redk[6], redk[7])));
    const float mN = qn[b * 4096 + nq] * (1.02f * Kb);
    float l_run = 0.f;

    f32x4 acc[4][4];
    #pragma unroll
    for (int ct = 0; ct < 4; ct++)
        #pragma unroll
        for (int nt = 0; nt < 4; nt++) { acc[ct][nt][0] = 0.f; acc[ct][nt][1] = 0.f; acc[ct][nt][2] = 0.f; acc[ct][nt][3] = 0.f; }
    const unsigned short* kTb = kT + (size_t)b * 4096 * 32;
    const unsigned short* vfb = vC + ((size_t)b * 64 << 14)
                              + (((8 * cw) + khw) << 9) + lane * 8;

    const int po  = 4 * (quad & 1);
    const int pg0 = ((4 * khw + (quad >> 1)) ^ (l16 & 7));
    const int pg1 = ((4 * khw + 2 + (quad >> 1)) ^ (l16 & 7));
    const int pgr = ((4 * khw + quad) ^ (l16 & 7)) << 3;

    FRAG avA[4], avB[4], kc0, kc1;

#define AV_LOAD(AV, CH) do { \
    const unsigned short* vfj = vfb + ((size_t)(CH) << 14); \
    AV[0].u = *(const uint4*)(vfj); \
    AV[1].u = *(const uint4*)(vfj + 1024); \
    AV[2].u = *(const uint4*)(vfj + 2048); \
    AV[3].u = *(const uint4*)(vfj + 3072); \
} while (0)

#define KC_LOAD(CH) do { \
    const int mo_ = (CH) << 6; \
    kc0.u = *(const uint4*)(kTb + (size_t)(mo_ + 16 * mt0 + l16) * 32 + quad * 8); \
    kc1.u = *(const uint4*)(kTb + (size_t)(mo_ + 16 * mt1 + l16) * 32 + quad * 8); \
} while (0)

#define QK_EXP_STORE(DST) do { \
    f32x4 z; z[0] = 0.f; z[1] = 0.f; z[2] = 0.f; z[3] = 0.f; \
    f32x4 e0 = __builtin_amdgcn_mfma_f32_16x16x32_bf16(kc0.s, qf.s, z, 0, 0, 0); \
    f32x4 e1 = __builtin_amdgcn_mfma_f32_16x16x32_bf16(kc1.s, qf.s, z, 0, 0, 0); \
    union { float f; unsigned int u; } p0, p1, p2, p3; \
    uint2 pkA, pkB; \
    p0.f = __expf(e0[0] - mN); p1.f = __expf(e0[1] - mN); \
    p2.f = __expf(e0[2] - mN); p3.f = __expf(e0[3] - mN); \
    l_run += (p0.f + p1.f) + (p2.f + p3.f); \
    pkA.x = __builtin_amdgcn_perm(p1.u, p0.u, 0x07060302u); \
    pkA.y = __builtin_amdgcn_perm(p3.u, p2.u, 0x07060302u); \
    p0.f = __expf(e1[0] - mN); p1.f = __expf(e1[1] - mN); \
    p2.f = __expf(e1[2] - mN); p3.f = __expf(e1[3] - mN); \
    l_run += (p0.f + p1.f) + (p2.f + p3.f); \
    pkB.x = __builtin_amdgcn_perm(p1.u, p0.u, 0x07060302u); \
    pkB.y = __builtin_amdgcn_perm(p3.u, p2.u, 0x07060302u); \
    *(uint2*)&PL[DST][16 * ntq + l16][(pg0 << 3) + po] = pkA; \
    *(uint2*)&PL[DST][16 * ntq + l16][(pg1 << 3) + po] = pkB; \
} while (0)

#define PV_STEP(AV, CUR) do { \
    FRAG bp[4]; \
    _Pragma("unroll") \
    for (int nt = 0; nt < 4; nt++) \
        bp[nt].u = *(const uint4*)&PL[CUR][16 * nt + l16][pgr]; \
    __builtin_amdgcn_s_setprio(1); \
    _Pragma("unroll") \
    for (int ct = 0; ct < 4; ct++) { \
        _Pragma("unroll") \
        for (int nt = 0; nt < 4; nt++) \
            acc[ct][nt] = __builtin_amdgcn_mfma_f32_16x16x32_bf16(AV[ct].s, bp[nt].s, acc[ct][nt], 0, 0, 0); \
    } \
    __builtin_amdgcn_s_setprio(0); \
} while (0)

    // --- prologue: av(0); QK(0)->PL[0]; kc for chunk 1 ---
    AV_LOAD(avA, 0);
    KC_LOAD(0);
    QK_EXP_STORE(0);
    KC_LOAD(1);

    for (int jj = 0; jj < 32; jj++) {
        const int j = 2 * jj;
        __syncthreads();
        {
            AV_LOAD(avB, j + 1);
            QK_EXP_STORE(1);
            if (j < 62) KC_LOAD(j + 2);
        }
        PV_STEP(avA, 0);
        __syncthreads();
        if (j < 62) {
            AV_LOAD(avA, j + 2);
            QK_EXP_STORE(0);
            if (j < 61) KC_LOAD(j + 3);
        }
        PV_STEP(avB, 1);
    }
#undef AV_LOAD
#undef KC_LOAD
#undef QK_EXP_STORE
#undef PV_STEP

    // l: reduce across quads -> per-(ntq,l16) half-sum.
    l_run += __shfl_xor(l_run, 16);
    l_run += __shfl_xor(l_run, 32);
    if (quad == 0) lsh[khw][16 * ntq + l16] = l_run;

    // residual gate factors for the epilogue
    if (t < 256) gsh[t] = g[(b << 8) + t];
    else if (t < 320) ssh[t - 256] = spg[(size_t)b * 4096 + qbase + (t - 256)];

    // --- epilogue: combine khw halves via SB, 2 c-stripe rounds ---
    const float gm = gamma[0];
    for (int s = 0; s < 2; s++) {
        __syncthreads();
        if (s == 0 && t < 64) ilsh[t] = 1.f / (lsh[0][t] + lsh[1][t]);
        if (khw == 0 && (cw >> 1) == s) {
            #pragma unroll
            for (int ct = 0; ct < 4; ct++)
                #pragma unroll
                for (int nt = 0; nt < 4; nt++)
                    #pragma unroll
                    for (int r = 0; r < 4; r++)
                        SB[64 * (cw & 1) + 16 * ct + 4 * quad + r][16 * nt + l16] = acc[ct][nt][r];
        }
        __syncthreads();
        if (khw == 1 && (cw >> 1) == s) {
            #pragma unroll
            for (int ct = 0; ct < 4; ct++)
                #pragma unroll
                for (int nt = 0; nt < 4; nt++)
                    #pragma unroll
                    for (int r = 0; r < 4; r++)
                        SB[64 * (cw & 1) + 16 * ct + 4 * quad + r][16 * nt + l16] += acc[ct][nt][r];
        }
        __syncthreads();
        // cooperative store: 128c x 64n
        #pragma unroll
        for (int pass = 0; pass < 4; pass++) {
            int cl = (t >> 4) + 32 * pass;
            int n4 = (t & 15) * 4;
            float4 vv = *(float4*)&SB[cl][n4];
            float4 il4 = *(float4*)&ilsh[n4];
            size_t idx = ((size_t)(b * 256 + 128 * s + cl)) * 4096 + qbase + n4;
            float4 xv = *(const float4*)(x + idx);
            float gc = gsh[128 * s + cl];
            float4 ss4 = *(float4*)&ssh[n4];
            float4 ov;
            ov.x = gm * vv.x * il4.x + xv.x * (gc * ss4.x);
            ov.y = gm * vv.y * il4.y + xv.y * (gc * ss4.y);
            ov.z = gm * vv.z * il4.z + xv.z * (gc * ss4.z);
            ov.w = gm * vv.w * il4.w + xv.w * (gc * ss4.w);
            *(float4*)(outp + idx) = ov;
        }
    }
}

// ---------------------------------------------------------------------------
extern "C" void kernel_launch(void* const* d_in, const int* in_sizes, int n_in,
                              void* d_out, int out_size, void* d_ws, size_t ws_size,
                              hipStream_t stream) {
    (void)in_sizes; (void)n_in; (void)out_size; (void)ws_size;
    const float* x    = (const float*)d_in[0];
    const float* W1   = (const float*)d_in[1];
    const float* b1   = (const float*)d_in[2];
    const float* W2   = (const float*)d_in[3];
    const float* b2   = (const float*)d_in[4];
    const float* Wq   = (const float*)d_in[5];
    const float* bq   = (const float*)d_in[6];
    const float* Wk   = (const float*)d_in[7];
    const float* bk   = (const float*)d_in[8];
    const float* Wv   = (const float*)d_in[9];
    const float* bv   = (const float*)d_in[10];
    const float* gam  = (const float*)d_in[11];
    const float* Wsp  = (const float*)d_in[12];
    const float* bn_g = (const float*)d_in[13];
    const float* bn_b = (const float*)d_in[14];
    const float* bn_m = (const float*)d_in[15];
    const float* bn_v = (const float*)d_in[16];

    float* ws = (float*)d_ws;
    float* bm2   = ws; ws += (size_t)4 * 256 * 1024;
    float* bm4   = ws; ws += (size_t)4 * 256 * 256;
    float* bm8   = ws; ws += (size_t)4 * 256 * 64;
    float* featA = ws; ws += 1024;
    float* fm1   = ws; ws += 1024;
    float* fm2   = ws; ws += 1024;
    float* fm4   = ws; ws += 1024;
    float* fm8   = ws; ws += 1024;
    float* g     = ws; ws += 1024;
    float* comp  = ws; ws += (size_t)4 * 2 * 4096;
    float* spg   = ws; ws += (size_t)4 * 4096;
    float* bm2b  = ws; ws += (size_t)4 * 256 * 1024;
    float* bm4b  = ws; ws += (size_t)4 * 256 * 256;
    float* bm8b  = ws; ws += (size_t)4 * 256 * 64;
    float* P2    = ws; ws += (size_t)4 * 320 * 1024;
    float* P4    = ws; ws += (size_t)4 * 320 * 256;
    float* P8    = ws; ws += (size_t)4 * 320 * 64;
    float* qn    = ws; ws += (size_t)4 * 4096;
    float* kn    = ws; ws += (size_t)4 * 4096;
    unsigned short* qT  = (unsigned short*)ws; ws += (size_t)4 * 4096 * 32 / 2;
    unsigned short* kT  = (unsigned short*)ws; ws += (size_t)4 * 4096 * 32 / 2;
    unsigned short* vCp = (unsigned short*)ws; ws += (size_t)4 * 64 * 16384 / 2;
    unsigned short* x2T = (unsigned short*)ws; ws += (size_t)4 * 4096 * 256 / 2;
    unsigned short* WB  = (unsigned short*)ws; ws += (size_t)320 * 256 / 2;

    // Stage 1: channel gate (pyramid + fused weight-cast)
    k_pyramid<<<1104, 256, 0, stream>>>(x, bm2, bm4, bm8,
                                        featA, fm1, fm2, fm4, fm8,
                                        Wq, Wk, Wv, WB);
    // Stage 2: spatial gate (k3 with fused channel-gate MLP; 8 waves)
    k3_comp<<<256, 512, 0, stream>>>(x, bm2, bm4, bm8,
                                     featA, fm1, fm2, fm4, fm8,
                                     W1, b1, W2, b2, g, comp);
    // Fused spgate-conv + gate + transpose + pool2 (k4 deleted), then pools
    k_x2tp<<<dim3(32, 4, 4), 256, 0, stream>>>(x, g, comp, Wsp,
                                               bn_g, bn_b, bn_m, bn_v,
                                               x2T, bm2b, spg);
    k_pool48<<<1024, 256, 0, stream>>>(bm2b, bm4b, bm8b);
    // Stage 3: q/k/v projections (+ per-token q/k norms)
    k6_gemm<<<dim3(13, 5, 4), 256, 0, stream>>>(Wq, Wk, Wv, bm2b, bm4b, bm8b, P2, P4, P8);
    k6m<<<640, 256, 0, stream>>>(WB, x2T, bq, bk, bv, P2, P4, P8, qT, kT, vCp, qn, kn);
    // Attention: single pass; shift bound + denominator computed in-kernel
    k7b_attn<<<256, 512, 0, stream>>>(qT, kT, vCp, qn, kn, x, g, spg, gam, (float*)d_out);
}